// Round 1
// baseline (5492.702 us; speedup 1.0000x reference)
//
#include <hip/hip_runtime.h>
#include <hip/hip_bf16.h>

// KGTN: GGNN over classifier weights + inner-product classifier.
// Round 1: correctness-first fp32 baseline. All GEMMs are 64x64x16 LDS-tiled
// fp32 (no MFMA yet). Deterministic two-stage L2 reduction.
//
// Shapes: h=1024, N=2048, B=8192, TIME_STEP=3.
// d_out: [8192*2048] output fp32, then [1] l2_reg.
// d_ws: nodes, init_nodes, zv, rv, hv, step_out (each N*h f32) + partials(1024)
//       = ~48 MB. av [N,2h] uses the front of d_out as scratch (dead before
//       the final GEMM rewrites d_out).

#define BM 64
#define BN 64
#define BK 16

// C[M,Ncols] = (ACC ? C + : ) A @ B
// TA=0: A[m][k] = A[m*lda + k]; TA=1: A[m][k] = A[k*lda + m]  (A stored transposed)
// TB=0: B[k][n] = B[k*ldb + n]; TB=1: B[k][n] = B[n*ldb + k]  (B stored transposed)
template <int TA, int TB, bool ACC>
__global__ __launch_bounds__(256) void gemm64(const float* __restrict__ A,
                                              const float* __restrict__ B,
                                              float* __restrict__ C,
                                              int M, int N, int K,
                                              int lda, int ldb, int ldc) {
    __shared__ float As[BK][BM + 1];
    __shared__ float Bs[BK][BN + 1];
    const int tid = threadIdx.x;
    const int tx = tid & 15;        // 0..15
    const int ty = tid >> 4;        // 0..15
    const int bm = blockIdx.y * BM;
    const int bn = blockIdx.x * BN;

    float acc[4][4] = {};

    for (int k0 = 0; k0 < K; k0 += BK) {
        // A tile: BM x BK = 1024 elems, 4 per thread
        #pragma unroll
        for (int i = 0; i < 4; ++i) {
            int idx = tid + i * 256;
            int m = idx / BK;
            int k = idx % BK;
            float v = TA ? A[(size_t)(k0 + k) * lda + (bm + m)]
                         : A[(size_t)(bm + m) * lda + (k0 + k)];
            As[k][m] = v;
        }
        // B tile: BK x BN = 1024 elems
        #pragma unroll
        for (int i = 0; i < 4; ++i) {
            int idx = tid + i * 256;
            int k = idx / BN;
            int n = idx % BN;
            float v = TB ? B[(size_t)(bn + n) * ldb + (k0 + k)]
                         : B[(size_t)(k0 + k) * ldb + (bn + n)];
            Bs[k][n] = v;
        }
        __syncthreads();
        #pragma unroll
        for (int k = 0; k < BK; ++k) {
            float a[4], b[4];
            #pragma unroll
            for (int i = 0; i < 4; ++i) a[i] = As[k][ty * 4 + i];
            #pragma unroll
            for (int j = 0; j < 4; ++j) b[j] = Bs[k][tx * 4 + j];
            #pragma unroll
            for (int i = 0; i < 4; ++i)
                #pragma unroll
                for (int j = 0; j < 4; ++j)
                    acc[i][j] += a[i] * b[j];
        }
        __syncthreads();
    }

    #pragma unroll
    for (int i = 0; i < 4; ++i) {
        int m = bm + ty * 4 + i;
        #pragma unroll
        for (int j = 0; j < 4; ++j) {
            int n = bn + tx * 4 + j;
            size_t off = (size_t)m * ldc + n;
            C[off] = ACC ? (C[off] + acc[i][j]) : acc[i][j];
        }
    }
}

// out0[c][r] = out1[c][r] = in[r][c]; in is [R,C] row-major.
__global__ void transpose2(const float* __restrict__ in, float* __restrict__ o0,
                           float* __restrict__ o1, int R, int C) {
    __shared__ float tile[32][33];
    int c0 = blockIdx.x * 32, r0 = blockIdx.y * 32;
    int tx = threadIdx.x, ty = threadIdx.y;   // 32 x 8
    #pragma unroll
    for (int i = 0; i < 32; i += 8)
        tile[ty + i][tx] = in[(size_t)(r0 + ty + i) * C + (c0 + tx)];
    __syncthreads();
    #pragma unroll
    for (int i = 0; i < 32; i += 8) {
        float v = tile[tx][ty + i];
        size_t o = (size_t)(c0 + ty + i) * R + (r0 + tx);
        o0[o] = v;
        o1[o] = v;
    }
}

// zv = sigmoid(zpre); rv_buf = sigmoid(rpre) * nodes   (rn stored over rv)
__global__ void gates_zr(float* __restrict__ zv, float* __restrict__ rv,
                         const float* __restrict__ nodes, int total) {
    int i = blockIdx.x * blockDim.x + threadIdx.x;
    if (i >= total) return;
    float z = 1.0f / (1.0f + expf(-zv[i]));
    zv[i] = z;
    float r = 1.0f / (1.0f + expf(-rv[i]));
    rv[i] = r * nodes[i];
}

// nodes = (1-zv)*nodes + zv*tanh(hpre)
__global__ void update_nodes(float* __restrict__ nodes, const float* __restrict__ zv,
                             const float* __restrict__ hpre, int total) {
    int i = blockIdx.x * blockDim.x + threadIdx.x;
    if (i >= total) return;
    float hvv = tanhf(hpre[i]);
    float z = zv[i];
    nodes[i] = (1.0f - z) * nodes[i] + z * hvv;
}

// step_out += bias (per column, ld=1024); per-block partial sum of squares.
__global__ __launch_bounds__(256) void bias_l2(float* __restrict__ s,
                                               const float* __restrict__ bias,
                                               float* __restrict__ partials) {
    __shared__ float red[256];
    int tid = threadIdx.x;
    int base = blockIdx.x * 2048;
    float sum = 0.0f;
    #pragma unroll
    for (int it = 0; it < 8; ++it) {
        int i = base + tid + it * 256;
        float v = s[i] + bias[i & 1023];
        s[i] = v;
        sum += v * v;
    }
    red[tid] = sum;
    __syncthreads();
    #pragma unroll
    for (int w = 128; w > 0; w >>= 1) {
        if (tid < w) red[tid] += red[tid + w];
        __syncthreads();
    }
    if (tid == 0) partials[blockIdx.x] = red[0];
}

__global__ __launch_bounds__(256) void reduce_final(const float* __restrict__ partials,
                                                    float* __restrict__ out) {
    __shared__ float red[256];
    int tid = threadIdx.x;
    red[tid] = partials[tid] + partials[tid + 256] + partials[tid + 512] + partials[tid + 768];
    __syncthreads();
    #pragma unroll
    for (int w = 128; w > 0; w >>= 1) {
        if (tid < w) red[tid] += red[tid + w];
        __syncthreads();
    }
    if (tid == 0) out[0] = red[0];
}

extern "C" void kernel_launch(void* const* d_in, const int* in_sizes, int n_in,
                              void* d_out, int out_size, void* d_ws, size_t ws_size,
                              hipStream_t stream) {
    const float* x   = (const float*)d_in[0];   // [8192,1024]
    const float* lfw = (const float*)d_in[1];   // [1024,2048]
    const float* inM = (const float*)d_in[2];   // [2048,2048]
    const float* w3w = (const float*)d_in[3];   // [2048,1024]
    const float* w3u = (const float*)d_in[4];   // [1024,1024]
    const float* w4w = (const float*)d_in[5];
    const float* w4u = (const float*)d_in[6];
    const float* w5w = (const float*)d_in[7];
    const float* w5u = (const float*)d_in[8];
    const float* fcw = (const float*)d_in[9];   // [2048,1024]
    const float* fcb = (const float*)d_in[10];  // [1024]
    float* out = (float*)d_out;

    const int h = 1024, N = 2048, B = 8192;
    const size_t NH = (size_t)N * h;

    float* ws         = (float*)d_ws;
    float* nodes      = ws;                 // [N,h]
    float* init_nodes = nodes + NH;         // [N,h]
    float* zv         = init_nodes + NH;    // [N,h]
    float* rv         = zv + NH;            // [N,h]
    float* hv         = rv + NH;            // [N,h]
    float* step_out   = hv + NH;            // [N,h]
    float* partials   = step_out + NH;      // [1024]
    float* av         = out;                // [N,2h] scratch in d_out (dead before final GEMM)

#define GEMM(TA, TB, ACC, Ap, Bp, Cp, M_, N_, K_, lda_, ldb_, ldc_)            \
    gemm64<TA, TB, ACC><<<dim3((N_) / BN, (M_) / BM), 256, 0, stream>>>(        \
        Ap, Bp, Cp, M_, N_, K_, lda_, ldb_, ldc_)

    // init_nodes = nodes = last_fc_weight^T
    transpose2<<<dim3(N / 32, h / 32), dim3(32, 8), 0, stream>>>(lfw, init_nodes, nodes, h, N);

    const int EB = 256;
    const int EG = (int)(NH / EB);

    for (int t = 0; t < 3; ++t) {
        // av = [in_matrix @ nodes | in_matrix^T @ nodes]   [N, 2h], ldc = 2h
        GEMM(0, 0, false, inM, nodes, av,        N, h, N, N, h, 2 * h);
        GEMM(1, 0, false, inM, nodes, av + h,    N, h, N, N, h, 2 * h);
        // zpre = av @ w3w + nodes @ w3u
        GEMM(0, 0, false, av,    w3w, zv, N, h, 2 * h, 2 * h, h, h);
        GEMM(0, 0, true,  nodes, w3u, zv, N, h, h,     h,     h, h);
        // rpre = av @ w4w + nodes @ w4u
        GEMM(0, 0, false, av,    w4w, rv, N, h, 2 * h, 2 * h, h, h);
        GEMM(0, 0, true,  nodes, w4u, rv, N, h, h,     h,     h, h);
        // zv = sigmoid(zpre); rv = sigmoid(rpre) * nodes
        gates_zr<<<EG, EB, 0, stream>>>(zv, rv, nodes, (int)NH);
        // hpre = av @ w5w + rn @ w5u
        GEMM(0, 0, false, av, w5w, hv, N, h, 2 * h, 2 * h, h, h);
        GEMM(0, 0, true,  rv, w5u, hv, N, h, h,     h,     h, h);
        // nodes = (1-zv)*nodes + zv*tanh(hpre)
        update_nodes<<<EG, EB, 0, stream>>>(nodes, zv, hv, (int)NH);
    }

    // step_out = nodes @ fcw[0:h,:] + init_nodes @ fcw[h:2h,:]
    GEMM(0, 0, false, nodes,      fcw,                 step_out, N, h, h, h, h, h);
    GEMM(0, 0, true,  init_nodes, fcw + (size_t)h * h, step_out, N, h, h, h, h, h);

    // step_out += bias; l2_reg = sum(step_out^2)  (deterministic 2-stage)
    bias_l2<<<1024, 256, 0, stream>>>(step_out, fcb, partials);
    reduce_final<<<1, 256, 0, stream>>>(partials, out + (size_t)B * N);

    // output = x @ step_out^T   [B, N]
    GEMM(0, 1, false, x, step_out, out, B, N, h, h, h, N);

#undef GEMM
}

// Round 2
// 840.546 us; speedup vs baseline: 6.5347x; 6.5347x over previous
//
#include <hip/hip_runtime.h>
#include <hip/hip_bf16.h>
#include <stdint.h>

// KGTN round 2: bf16 MFMA GEMMs (m97 structure: 128x128 tile, BK=64, 4 waves,
// global_load_lds width-16, mfma_f32_16x16x32_bf16, B^T operands).
// fp32 master state for nodes; fp32 elementwise; fp32 accumulation everywhere.
// K-fusion: avn = [in@nodes | inT@nodes | nodes_bf] (2048x3072 bf16) so
// z&r gates = ONE GEMM K=3072 (N=2048 covers both), h = ONE GEMM K=3072.
// zr / hpre / step_out scratch alias the front of d_out (dead before the
// final GEMM rewrites all of d_out).

typedef __attribute__((ext_vector_type(8))) short bf16x8;
typedef __attribute__((ext_vector_type(4))) float f32x4;
typedef __attribute__((ext_vector_type(4))) ushort u16x4;

typedef __attribute__((address_space(3))) void lds_void;
typedef const __attribute__((address_space(1))) void gbl_void;

__device__ __forceinline__ ushort f2b(float v) {
    union { float f; uint32_t u; } c; c.f = v;
    uint32_t u = c.u + 0x7FFFu + ((c.u >> 16) & 1u);   // RNE; inputs finite
    return (ushort)(u >> 16);
}

// C[M,N] = A[M,K] @ B[K,N], A row-major bf16 (lda), Bt = B^T [N,K] row-major
// bf16 (ldb). Grid: x = N/128, y = M/128. C fp32 or bf16 (ldc).
template <bool OUT_BF16>
__global__ __launch_bounds__(256) void gemm_bf16(
    const ushort* __restrict__ A, const ushort* __restrict__ Bt,
    void* __restrict__ Cv, int K, int lda, int ldb, int ldc)
{
    __shared__ ushort As[128 * 64];
    __shared__ ushort Bs[128 * 64];
    const int tid  = threadIdx.x;
    const int lane = tid & 63;
    const int wave = tid >> 6;
    const int wr = (wave >> 1) * 64;       // wave's 64-row band
    const int wc = (wave & 1) * 64;        // wave's 64-col band
    const long bm = (long)blockIdx.y * 128;
    const long bn = (long)blockIdx.x * 128;

    const int l15  = lane & 15;
    const int kg8  = (lane >> 4) * 8;      // k-group offset within 32
    const int srow = lane >> 3;            // staging: row within 8-row slot
    const int skb  = (lane & 7) * 8;       // staging: bf16 col (16B per lane)

    f32x4 acc[4][4] = {};

    for (int k0 = 0; k0 < K; k0 += 64) {
        __syncthreads();                   // prev compute done before overwrite
        #pragma unroll
        for (int p = 0; p < 4; ++p) {
            const int slot = wave * 4 + p; // 0..15 -> 8 rows each
            const int row  = slot * 8 + srow;
            const ushort* ga = A  + (bm + row) * (long)lda + (k0 + skb);
            const ushort* gb = Bt + (bn + row) * (long)ldb + (k0 + skb);
            __builtin_amdgcn_global_load_lds((gbl_void*)ga,
                (lds_void*)(As + slot * 512), 16, 0, 0);
            __builtin_amdgcn_global_load_lds((gbl_void*)gb,
                (lds_void*)(Bs + slot * 512), 16, 0, 0);
        }
        __syncthreads();                   // drains vmcnt -> LDS visible
        #pragma unroll
        for (int kk = 0; kk < 2; ++kk) {
            bf16x8 af[4], bf[4];
            #pragma unroll
            for (int m = 0; m < 4; ++m)
                af[m] = *(const bf16x8*)(As + (wr + m * 16 + l15) * 64 + kk * 32 + kg8);
            #pragma unroll
            for (int n = 0; n < 4; ++n)
                bf[n] = *(const bf16x8*)(Bs + (wc + n * 16 + l15) * 64 + kk * 32 + kg8);
            #pragma unroll
            for (int m = 0; m < 4; ++m)
                #pragma unroll
                for (int n = 0; n < 4; ++n)
                    acc[m][n] = __builtin_amdgcn_mfma_f32_16x16x32_bf16(
                        af[m], bf[n], acc[m][n], 0, 0, 0);
        }
    }

    // C/D layout: col = lane&15, row = (lane>>4)*4 + reg   [m89-verified]
    const int cr0 = (lane >> 4) * 4;
    #pragma unroll
    for (int m = 0; m < 4; ++m) {
        #pragma unroll
        for (int j = 0; j < 4; ++j) {
            const long r = bm + wr + m * 16 + cr0 + j;
            if (OUT_BF16) {
                ushort* C = (ushort*)Cv;
                #pragma unroll
                for (int n = 0; n < 4; ++n)
                    C[r * (long)ldc + bn + wc + n * 16 + l15] = f2b(acc[m][n][j]);
            } else {
                float* C = (float*)Cv;
                #pragma unroll
                for (int n = 0; n < 4; ++n)
                    C[r * (long)ldc + bn + wc + n * 16 + l15] = acc[m][n][j];
            }
        }
    }
}

// fp32 -> bf16 elementwise, 4 elems/thread. n4 = total/4.
__global__ __launch_bounds__(256) void cvt_bf16_k(const float* __restrict__ src,
                                                  ushort* __restrict__ dst, long n4) {
    long i = (long)blockIdx.x * 256 + threadIdx.x;
    if (i >= n4) return;
    f32x4 v = *(const f32x4*)(src + i * 4);
    u16x4 o;
    #pragma unroll
    for (int j = 0; j < 4; ++j) o[j] = f2b(v[j]);
    *(u16x4*)(dst + i * 4) = o;
}

// dst[c*dld + r] = bf16(src[r*C + c]). Grid (C/32, R/32), block 256 (32x8).
__global__ __launch_bounds__(256) void transpose_cvt(const float* __restrict__ src,
                                                     ushort* __restrict__ dst,
                                                     int R, int C, int dld) {
    __shared__ float t[32][33];
    const int c0 = blockIdx.x * 32, r0 = blockIdx.y * 32;
    const int tx = threadIdx.x & 31, ty = threadIdx.x >> 5;
    #pragma unroll
    for (int i = 0; i < 32; i += 8)
        t[ty + i][tx] = src[(long)(r0 + ty + i) * C + c0 + tx];
    __syncthreads();
    #pragma unroll
    for (int i = 0; i < 32; i += 8)
        dst[(long)(c0 + ty + i) * dld + r0 + tx] = f2b(t[tx][ty + i]);
}

// From lfw [1024(h), 2048(N)]: nodesT_bf[h][N] (direct cvt), nodes f32 [N][h],
// nodes_bf into avn cols 2048:3072, init_bf into ninit cols 1024:2048.
__global__ __launch_bounds__(256) void init_nodes_k(const float* __restrict__ lfw,
        ushort* __restrict__ nodesT, float* __restrict__ nodes,
        ushort* __restrict__ avn, ushort* __restrict__ ninit) {
    __shared__ float t[32][33];
    const int n0 = blockIdx.x * 32, h0 = blockIdx.y * 32;
    const int tx = threadIdx.x & 31, ty = threadIdx.x >> 5;
    #pragma unroll
    for (int i = 0; i < 32; i += 8) {
        float v = lfw[(long)(h0 + ty + i) * 2048 + n0 + tx];
        nodesT[(long)(h0 + ty + i) * 2048 + n0 + tx] = f2b(v);
        t[ty + i][tx] = v;
    }
    __syncthreads();
    #pragma unroll
    for (int i = 0; i < 32; i += 8) {
        const int n = n0 + ty + i, hh = h0 + tx;
        float v = t[tx][ty + i];
        nodes[(long)n * 1024 + hh] = v;
        ushort b = f2b(v);
        avn[(long)n * 3072 + 2048 + hh] = b;
        ninit[(long)n * 2048 + 1024 + hh] = b;
    }
}

// zv = sigmoid(zpre); rn_bf = bf16(sigmoid(rpre) * nodes) -> avn cols 2048:3072
__global__ __launch_bounds__(256) void gates_zr_k(const float* __restrict__ zr,
        const float* __restrict__ nodes, float* __restrict__ zv,
        ushort* __restrict__ avn) {
    const long i = (long)blockIdx.x * 256 + threadIdx.x;   // over [2048,1024]
    const int r = (int)(i >> 10), c = (int)(i & 1023);
    const float zp = zr[(long)r * 2048 + c];
    const float rp = zr[(long)r * 2048 + 1024 + c];
    const float z = 1.f / (1.f + __expf(-zp));
    zv[i] = z;
    const float rn = (1.f / (1.f + __expf(-rp))) * nodes[i];
    avn[(long)r * 3072 + 2048 + c] = f2b(rn);
}

// nodes = (1-z)*nodes + z*tanh(hpre); emit nodes_bf (avn cols 2048:3072,
// ninit cols 0:1024) and nodesT_bf (transposed). Grid (1024/32, 2048/32).
__global__ __launch_bounds__(256) void update_nodes_k(float* __restrict__ nodes,
        const float* __restrict__ zv, const float* __restrict__ hpre,
        ushort* __restrict__ avn, ushort* __restrict__ ninit,
        ushort* __restrict__ nodesT) {
    __shared__ float t[32][33];
    const int c0 = blockIdx.x * 32, r0 = blockIdx.y * 32;
    const int tx = threadIdx.x & 31, ty = threadIdx.x >> 5;
    #pragma unroll
    for (int i = 0; i < 32; i += 8) {
        const int r = r0 + ty + i, c = c0 + tx;
        const long idx = (long)r * 1024 + c;
        const float z = zv[idx];
        const float nn = (1.f - z) * nodes[idx] + z * tanhf(hpre[idx]);
        nodes[idx] = nn;
        const ushort b = f2b(nn);
        avn[(long)r * 3072 + 2048 + c] = b;
        ninit[(long)r * 2048 + c] = b;
        t[ty + i][tx] = nn;
    }
    __syncthreads();
    #pragma unroll
    for (int i = 0; i < 32; i += 8)
        nodesT[(long)(c0 + ty + i) * 2048 + r0 + tx] = f2b(t[tx][ty + i]);
}

// v = step_out + bias; so_bf = bf16(v); partial sums of v^2. 1024 blocks x 2048.
__global__ __launch_bounds__(256) void bias_l2(const float* __restrict__ s,
        const float* __restrict__ bias, ushort* __restrict__ so_bf,
        float* __restrict__ partials) {
    __shared__ float red[256];
    const int tid = threadIdx.x;
    const long base = (long)blockIdx.x * 2048;
    float sum = 0.f;
    #pragma unroll
    for (int it = 0; it < 8; ++it) {
        const long i = base + tid + it * 256;
        const float v = s[i] + bias[i & 1023];
        so_bf[i] = f2b(v);
        sum += v * v;
    }
    red[tid] = sum;
    __syncthreads();
    #pragma unroll
    for (int w = 128; w > 0; w >>= 1) {
        if (tid < w) red[tid] += red[tid + w];
        __syncthreads();
    }
    if (tid == 0) partials[blockIdx.x] = red[0];
}

__global__ __launch_bounds__(256) void reduce_final(const float* __restrict__ partials,
                                                    float* __restrict__ out) {
    __shared__ float red[256];
    const int tid = threadIdx.x;
    red[tid] = partials[tid] + partials[tid + 256] + partials[tid + 512] + partials[tid + 768];
    __syncthreads();
    #pragma unroll
    for (int w = 128; w > 0; w >>= 1) {
        if (tid < w) red[tid] += red[tid + w];
        __syncthreads();
    }
    if (tid == 0) out[0] = red[0];
}

extern "C" void kernel_launch(void* const* d_in, const int* in_sizes, int n_in,
                              void* d_out, int out_size, void* d_ws, size_t ws_size,
                              hipStream_t stream) {
    const float* x   = (const float*)d_in[0];   // [8192,1024]
    const float* lfw = (const float*)d_in[1];   // [1024,2048]
    const float* inM = (const float*)d_in[2];   // [2048,2048]
    const float* w3w = (const float*)d_in[3];   // [2048,1024]
    const float* w3u = (const float*)d_in[4];   // [1024,1024]
    const float* w4w = (const float*)d_in[5];
    const float* w4u = (const float*)d_in[6];
    const float* w5w = (const float*)d_in[7];
    const float* w5u = (const float*)d_in[8];
    const float* fcw = (const float*)d_in[9];   // [2048,1024]
    const float* fcb = (const float*)d_in[10];  // [1024]
    float* out = (float*)d_out;

    const int B = 8192, N = 2048;

    // d_out front as fp32 scratch (dead before final GEMM rewrites d_out):
    float* zr       = out;                       // [2048,2048]
    float* hpre     = out + 4194304l;            // [2048,1024]
    float* step_out = out + 6291456l;            // [2048,1024]  (total 32MB < 64MB)

    char* p = (char*)d_ws;
    auto alloc = [&](size_t bytes) {
        char* r = p; p += (bytes + 255) & ~(size_t)255; return r;
    };
    float*  nodes    = (float*)alloc(2097152ull * 4);   // [2048,1024]
    float*  zv       = (float*)alloc(2097152ull * 4);   // [2048,1024]
    float*  partials = (float*)alloc(1024 * 4);
    ushort* avn      = (ushort*)alloc(6291456ull * 2);  // [2048,3072] bf16
    ushort* nodesT   = (ushort*)alloc(2097152ull * 2);  // [1024,2048] bf16
    ushort* ninit    = (ushort*)alloc(4194304ull * 2);  // [2048,2048] bf16
    ushort* inM_bf   = (ushort*)alloc(4194304ull * 2);  // [2048,2048]
    ushort* inMT_bf  = (ushort*)alloc(4194304ull * 2);  // [2048,2048]
    ushort* Wzr_t    = (ushort*)alloc(6291456ull * 2);  // [2048,3072]
    ushort* W5_t     = (ushort*)alloc(3145728ull * 2);  // [1024,3072]
    ushort* fcw_t    = (ushort*)alloc(2097152ull * 2);  // [1024,2048]
    ushort* x_bf     = (ushort*)alloc(8388608ull * 2);  // [8192,1024]
    ushort* so_bf    = (ushort*)alloc(2097152ull * 2);  // [2048,1024]

    const dim3 tb(256);

    // ---- prep (runs every call; ~160MB traffic ~ 35us) ----
    cvt_bf16_k<<<8192, tb, 0, stream>>>(x, x_bf, 2097152);
    cvt_bf16_k<<<4096, tb, 0, stream>>>(inM, inM_bf, 1048576);
    transpose_cvt<<<dim3(64, 64), tb, 0, stream>>>(inM, inMT_bf, 2048, 2048, 2048);
    transpose_cvt<<<dim3(32, 64), tb, 0, stream>>>(w3w, Wzr_t,                    2048, 1024, 3072);
    transpose_cvt<<<dim3(32, 32), tb, 0, stream>>>(w3u, Wzr_t + 2048,             1024, 1024, 3072);
    transpose_cvt<<<dim3(32, 64), tb, 0, stream>>>(w4w, Wzr_t + 3145728l,         2048, 1024, 3072);
    transpose_cvt<<<dim3(32, 32), tb, 0, stream>>>(w4u, Wzr_t + 3145728l + 2048,  1024, 1024, 3072);
    transpose_cvt<<<dim3(32, 64), tb, 0, stream>>>(w5w, W5_t,                     2048, 1024, 3072);
    transpose_cvt<<<dim3(32, 32), tb, 0, stream>>>(w5u, W5_t + 2048,              1024, 1024, 3072);
    transpose_cvt<<<dim3(32, 64), tb, 0, stream>>>(fcw, fcw_t,                    2048, 1024, 2048);
    init_nodes_k<<<dim3(64, 32), tb, 0, stream>>>(lfw, nodesT, nodes, avn, ninit);

    // ---- GGNN time steps ----
    for (int t = 0; t < 3; ++t) {
        // avn[:,0:1024] = in@nodes ; avn[:,1024:2048] = inT@nodes   (bf16 out)
        gemm_bf16<true ><<<dim3( 8, 16), tb, 0, stream>>>(inM_bf,  nodesT, avn,        2048, 2048, 2048, 3072);
        gemm_bf16<true ><<<dim3( 8, 16), tb, 0, stream>>>(inMT_bf, nodesT, avn + 1024, 2048, 2048, 2048, 3072);
        // zr[:,0:1024]=zpre, [:,1024:2048]=rpre  = avn @ [w3|w4] (K=3072)
        gemm_bf16<false><<<dim3(16, 16), tb, 0, stream>>>(avn, Wzr_t, zr,   3072, 3072, 3072, 2048);
        gates_zr_k<<<8192, tb, 0, stream>>>(zr, nodes, zv, avn);
        // hpre = [av|rn] @ [w5w|w5u]  (K=3072)
        gemm_bf16<false><<<dim3( 8, 16), tb, 0, stream>>>(avn, W5_t, hpre,  3072, 3072, 3072, 1024);
        update_nodes_k<<<dim3(32, 64), tb, 0, stream>>>(nodes, zv, hpre, avn, ninit, nodesT);
    }

    // step_out = [nodes|init] @ fc_out_w  (K=2048)
    gemm_bf16<false><<<dim3( 8, 16), tb, 0, stream>>>(ninit, fcw_t, step_out, 2048, 2048, 2048, 1024);
    bias_l2<<<1024, tb, 0, stream>>>(step_out, fcb, so_bf, partials);
    reduce_final<<<1, tb, 0, stream>>>(partials, out + (long)B * N);
    // output = x @ step_out^T : A=x_bf [8192,1024], Bt=so_bf [2048,1024]
    gemm_bf16<false><<<dim3(16, 64), tb, 0, stream>>>(x_bf, so_bf, out, 1024, 1024, 1024, 2048);
}

// Round 3
// 552.705 us; speedup vs baseline: 9.9379x; 1.5208x over previous
//
#include <hip/hip_runtime.h>
#include <hip/hip_bf16.h>
#include <stdint.h>

// KGTN round 3: deep-pipelined 128x128 bf16 MFMA GEMM for 1-block/CU regime.
// 4 LDS buffers (128 KiB), depth-3 prefetch, counted vmcnt(16) (never 0 in
// loop), one raw s_barrier per K-step, T2 XOR-swizzle (write-side via
// pre-swizzled global source granule, read-side via swizzled granule),
// T5 setprio around MFMA cluster. avn pair fused via blockIdx.z; h and
// step_out GEMMs split-K x2 (partials summed in elementwise consumers).

typedef __attribute__((ext_vector_type(8))) short bf16x8;
typedef __attribute__((ext_vector_type(4))) float f32x4;
typedef __attribute__((ext_vector_type(4))) ushort u16x4;

typedef __attribute__((address_space(3))) void lds_void;
typedef const __attribute__((address_space(1))) void gbl_void;

__device__ __forceinline__ ushort f2b(float v) {
    union { float f; uint32_t u; } c; c.f = v;
    uint32_t u = c.u + 0x7FFFu + ((c.u >> 16) & 1u);   // RNE; inputs finite
    return (ushort)(u >> 16);
}

// C[M,N] (+ z-variants) = A[M,K] @ B[K,N]; A row-major bf16 (lda),
// Bt = B^T [N,K] row-major bf16 (ldb). Grid: x=N/128, y=M/128, z in {1,2}.
// z selects A0/A1, offsets A,Bt by z*aKoff (elems along K), C by z*cOff.
template <bool OUT_BF16>
__global__ __launch_bounds__(256) void gemm_p3(
    const ushort* __restrict__ A0, const ushort* __restrict__ A1,
    const ushort* __restrict__ Bt, void* __restrict__ Cv,
    int K, int lda, int ldb, int ldc, long aKoff, long cOff)
{
    __shared__ ushort As[4 * 8192];
    __shared__ ushort Bs[4 * 8192];
    const int tid  = threadIdx.x;
    const int lane = tid & 63;
    const int wave = tid >> 6;
    const int wr = (wave >> 1) * 64;
    const int wc = (wave & 1) * 64;
    const long bm = (long)blockIdx.y * 128;
    const long bn = (long)blockIdx.x * 128;
    const int z  = blockIdx.z;

    const ushort* A  = (z ? A1 : A0) + (long)z * aKoff;
    const ushort* Bp = Bt + (long)z * aKoff;

    const int l15  = lane & 15;
    const int kg   = lane >> 4;                    // 0..3
    const int srow = lane >> 3;                    // 0..7
    const int gsw  = ((lane & 7) ^ srow) & 7;      // swizzled source granule

    f32x4 acc[4][4] = {};

    // stage one BK=64 K-tile into LDS buffer `buf` (8 gload_lds per wave)
    auto STAGE = [&](int k0, int buf) {
        #pragma unroll
        for (int p = 0; p < 4; ++p) {
            const int slot = wave * 4 + p;         // 16 slots x 8 rows
            const int row  = slot * 8 + srow;
            const ushort* ga = A  + (bm + row) * (long)lda + (k0 + gsw * 8);
            const ushort* gb = Bp + (bn + row) * (long)ldb + (k0 + gsw * 8);
            __builtin_amdgcn_global_load_lds((gbl_void*)ga,
                (lds_void*)(As + buf * 8192 + slot * 512), 16, 0, 0);
            __builtin_amdgcn_global_load_lds((gbl_void*)gb,
                (lds_void*)(Bs + buf * 8192 + slot * 512), 16, 0, 0);
        }
    };

    auto COMPUTE = [&](int buf) {
        const ushort* as = As + buf * 8192;
        const ushort* bs = Bs + buf * 8192;
        #pragma unroll
        for (int kk = 0; kk < 2; ++kk) {
            const int ph = (((kk * 4 + kg) ^ (lane & 7)) & 7) * 8;  // swizzled granule
            bf16x8 af[4], bv[4];
            #pragma unroll
            for (int m = 0; m < 4; ++m)
                af[m] = *(const bf16x8*)(as + (wr + m * 16 + l15) * 64 + ph);
            #pragma unroll
            for (int n = 0; n < 4; ++n)
                bv[n] = *(const bf16x8*)(bs + (wc + n * 16 + l15) * 64 + ph);
            __builtin_amdgcn_s_setprio(1);
            #pragma unroll
            for (int m = 0; m < 4; ++m)
                #pragma unroll
                for (int n = 0; n < 4; ++n)
                    acc[m][n] = __builtin_amdgcn_mfma_f32_16x16x32_bf16(
                        af[m], bv[n], acc[m][n], 0, 0, 0);
            __builtin_amdgcn_s_setprio(0);
        }
    };

#define SYNC(VM)                                            \
    __builtin_amdgcn_sched_barrier(0);                      \
    asm volatile("s_waitcnt vmcnt(" #VM ")" ::: "memory");  \
    __builtin_amdgcn_s_barrier();                           \
    __builtin_amdgcn_sched_barrier(0)

    const int T = K >> 6;                  // 16..48, always >= 4
    STAGE(0, 0); STAGE(64, 1); STAGE(128, 2);
    int buf = 0;
    for (int t = 0; t < T - 3; ++t) {
        SYNC(16);                          // tile t landed (all waves)
        STAGE((t + 3) * 64, (buf + 3) & 3);
        COMPUTE(buf);
        buf = (buf + 1) & 3;
    }
    SYNC(16); COMPUTE(buf); buf = (buf + 1) & 3;   // t = T-3
    SYNC(8);  COMPUTE(buf); buf = (buf + 1) & 3;   // t = T-2
    SYNC(0);  COMPUTE(buf);                        // t = T-1
#undef SYNC

    // C/D layout: col = lane&15, row = (lane>>4)*4 + reg   [m89-verified]
    const int cr0 = (lane >> 4) * 4;
    #pragma unroll
    for (int m = 0; m < 4; ++m) {
        #pragma unroll
        for (int j = 0; j < 4; ++j) {
            const long r = bm + wr + m * 16 + cr0 + j;
            if (OUT_BF16) {
                ushort* C = (ushort*)Cv + (long)z * cOff;
                #pragma unroll
                for (int n = 0; n < 4; ++n)
                    C[r * (long)ldc + bn + wc + n * 16 + l15] = f2b(acc[m][n][j]);
            } else {
                float* C = (float*)Cv + (long)z * cOff;
                #pragma unroll
                for (int n = 0; n < 4; ++n)
                    C[r * (long)ldc + bn + wc + n * 16 + l15] = acc[m][n][j];
            }
        }
    }
}

// fp32 -> bf16 elementwise, 4 elems/thread. n4 = total/4.
__global__ __launch_bounds__(256) void cvt_bf16_k(const float* __restrict__ src,
                                                  ushort* __restrict__ dst, long n4) {
    long i = (long)blockIdx.x * 256 + threadIdx.x;
    if (i >= n4) return;
    f32x4 v = *(const f32x4*)(src + i * 4);
    u16x4 o;
    #pragma unroll
    for (int j = 0; j < 4; ++j) o[j] = f2b(v[j]);
    *(u16x4*)(dst + i * 4) = o;
}

// dst[c*dld + r] = bf16(src[r*C + c]). Grid (C/32, R/32), block 256.
__global__ __launch_bounds__(256) void transpose_cvt(const float* __restrict__ src,
                                                     ushort* __restrict__ dst,
                                                     int R, int C, int dld) {
    __shared__ float t[32][33];
    const int c0 = blockIdx.x * 32, r0 = blockIdx.y * 32;
    const int tx = threadIdx.x & 31, ty = threadIdx.x >> 5;
    #pragma unroll
    for (int i = 0; i < 32; i += 8)
        t[ty + i][tx] = src[(long)(r0 + ty + i) * C + c0 + tx];
    __syncthreads();
    #pragma unroll
    for (int i = 0; i < 32; i += 8)
        dst[(long)(c0 + ty + i) * dld + r0 + tx] = f2b(t[tx][ty + i]);
}

// From lfw [1024(h), 2048(N)]: nodesT_bf[h][N], nodes f32 [N][h],
// nodes_bf -> avn cols 2048:3072, init_bf -> ninit cols 1024:2048.
__global__ __launch_bounds__(256) void init_nodes_k(const float* __restrict__ lfw,
        ushort* __restrict__ nodesT, float* __restrict__ nodes,
        ushort* __restrict__ avn, ushort* __restrict__ ninit) {
    __shared__ float t[32][33];
    const int n0 = blockIdx.x * 32, h0 = blockIdx.y * 32;
    const int tx = threadIdx.x & 31, ty = threadIdx.x >> 5;
    #pragma unroll
    for (int i = 0; i < 32; i += 8) {
        float v = lfw[(long)(h0 + ty + i) * 2048 + n0 + tx];
        nodesT[(long)(h0 + ty + i) * 2048 + n0 + tx] = f2b(v);
        t[ty + i][tx] = v;
    }
    __syncthreads();
    #pragma unroll
    for (int i = 0; i < 32; i += 8) {
        const int n = n0 + ty + i, hh = h0 + tx;
        float v = t[tx][ty + i];
        nodes[(long)n * 1024 + hh] = v;
        ushort b = f2b(v);
        avn[(long)n * 3072 + 2048 + hh] = b;
        ninit[(long)n * 2048 + 1024 + hh] = b;
    }
}

// zv = sigmoid(zpre); rn_bf = bf16(sigmoid(rpre)*nodes) -> avn cols 2048:3072
__global__ __launch_bounds__(256) void gates_zr_k(const float* __restrict__ zr,
        const float* __restrict__ nodes, float* __restrict__ zv,
        ushort* __restrict__ avn) {
    const long i = (long)blockIdx.x * 256 + threadIdx.x;   // over [2048,1024]
    const int r = (int)(i >> 10), c = (int)(i & 1023);
    const float zp = zr[(long)r * 2048 + c];
    const float rp = zr[(long)r * 2048 + 1024 + c];
    const float z = 1.f / (1.f + __expf(-zp));
    zv[i] = z;
    const float rn = (1.f / (1.f + __expf(-rp))) * nodes[i];
    avn[(long)r * 3072 + 2048 + c] = f2b(rn);
}

// nodes = (1-z)*nodes + z*tanh(hp0+hp1); emit nodes_bf + transposed copy.
__global__ __launch_bounds__(256) void update_nodes_k(float* __restrict__ nodes,
        const float* __restrict__ zv, const float* __restrict__ hp,
        ushort* __restrict__ avn, ushort* __restrict__ ninit,
        ushort* __restrict__ nodesT) {
    __shared__ float t[32][33];
    const int c0 = blockIdx.x * 32, r0 = blockIdx.y * 32;
    const int tx = threadIdx.x & 31, ty = threadIdx.x >> 5;
    #pragma unroll
    for (int i = 0; i < 32; i += 8) {
        const int r = r0 + ty + i, c = c0 + tx;
        const long idx = (long)r * 1024 + c;
        const float z = zv[idx];
        const float hsum = hp[idx] + hp[idx + 2097152];
        const float nn = (1.f - z) * nodes[idx] + z * tanhf(hsum);
        nodes[idx] = nn;
        const ushort b = f2b(nn);
        avn[(long)r * 3072 + 2048 + c] = b;
        ninit[(long)r * 2048 + c] = b;
        t[ty + i][tx] = nn;
    }
    __syncthreads();
    #pragma unroll
    for (int i = 0; i < 32; i += 8)
        nodesT[(long)(c0 + ty + i) * 2048 + r0 + tx] = f2b(t[tx][ty + i]);
}

// v = sop0+sop1+bias; so_bf = bf16(v); partial sums of v^2. 1024 blocks.
__global__ __launch_bounds__(256) void bias_l2(const float* __restrict__ s,
        const float* __restrict__ bias, ushort* __restrict__ so_bf,
        float* __restrict__ partials) {
    __shared__ float red[256];
    const int tid = threadIdx.x;
    const long base = (long)blockIdx.x * 2048;
    float sum = 0.f;
    #pragma unroll
    for (int it = 0; it < 8; ++it) {
        const long i = base + tid + it * 256;
        const float v = s[i] + s[i + 2097152] + bias[i & 1023];
        so_bf[i] = f2b(v);
        sum += v * v;
    }
    red[tid] = sum;
    __syncthreads();
    #pragma unroll
    for (int w = 128; w > 0; w >>= 1) {
        if (tid < w) red[tid] += red[tid + w];
        __syncthreads();
    }
    if (tid == 0) partials[blockIdx.x] = red[0];
}

__global__ __launch_bounds__(256) void reduce_final(const float* __restrict__ partials,
                                                    float* __restrict__ out) {
    __shared__ float red[256];
    const int tid = threadIdx.x;
    red[tid] = partials[tid] + partials[tid + 256] + partials[tid + 512] + partials[tid + 768];
    __syncthreads();
    #pragma unroll
    for (int w = 128; w > 0; w >>= 1) {
        if (tid < w) red[tid] += red[tid + w];
        __syncthreads();
    }
    if (tid == 0) out[0] = red[0];
}

extern "C" void kernel_launch(void* const* d_in, const int* in_sizes, int n_in,
                              void* d_out, int out_size, void* d_ws, size_t ws_size,
                              hipStream_t stream) {
    const float* x   = (const float*)d_in[0];   // [8192,1024]
    const float* lfw = (const float*)d_in[1];   // [1024,2048]
    const float* inM = (const float*)d_in[2];   // [2048,2048]
    const float* w3w = (const float*)d_in[3];
    const float* w3u = (const float*)d_in[4];
    const float* w4w = (const float*)d_in[5];
    const float* w4u = (const float*)d_in[6];
    const float* w5w = (const float*)d_in[7];
    const float* w5u = (const float*)d_in[8];
    const float* fcw = (const float*)d_in[9];
    const float* fcb = (const float*)d_in[10];
    float* out = (float*)d_out;

    const int B = 8192, N = 2048;
    const long NH = 2097152;

    // d_out front as fp32 scratch (dead before final GEMM rewrites d_out):
    float* zrbuf = out;                 // [2048,2048]
    float* hpre  = out + 4194304l;      // 2x [2048,1024]
    float* sop   = out + 8388608l;      // 2x [2048,1024]

    char* p = (char*)d_ws;
    auto alloc = [&](size_t bytes) {
        char* r = p; p += (bytes + 255) & ~(size_t)255; return r;
    };
    float*  nodes    = (float*)alloc(NH * 4);
    float*  zv       = (float*)alloc(NH * 4);
    float*  partials = (float*)alloc(1024 * 4);
    ushort* avn      = (ushort*)alloc(6291456ull * 2);  // [2048,3072]
    ushort* nodesT   = (ushort*)alloc(NH * 2);          // [1024,2048]
    ushort* ninit    = (ushort*)alloc(4194304ull * 2);  // [2048,2048]
    ushort* inM_bf   = (ushort*)alloc(4194304ull * 2);
    ushort* inMT_bf  = (ushort*)alloc(4194304ull * 2);
    ushort* Wzr_t    = (ushort*)alloc(6291456ull * 2);  // [2048,3072]
    ushort* W5_t     = (ushort*)alloc(3145728ull * 2);  // [1024,3072]
    ushort* fcw_t    = (ushort*)alloc(NH * 2);          // [1024,2048]
    ushort* x_bf     = (ushort*)alloc(8388608ull * 2);  // [8192,1024]
    ushort* so_bf    = (ushort*)alloc(NH * 2);          // [2048,1024]

    const dim3 tb(256);

    // ---- prep ----
    cvt_bf16_k<<<8192, tb, 0, stream>>>(x, x_bf, 2097152);
    cvt_bf16_k<<<4096, tb, 0, stream>>>(inM, inM_bf, 1048576);
    transpose_cvt<<<dim3(64, 64), tb, 0, stream>>>(inM, inMT_bf, 2048, 2048, 2048);
    transpose_cvt<<<dim3(32, 64), tb, 0, stream>>>(w3w, Wzr_t,                    2048, 1024, 3072);
    transpose_cvt<<<dim3(32, 32), tb, 0, stream>>>(w3u, Wzr_t + 2048,             1024, 1024, 3072);
    transpose_cvt<<<dim3(32, 64), tb, 0, stream>>>(w4w, Wzr_t + 3145728l,         2048, 1024, 3072);
    transpose_cvt<<<dim3(32, 32), tb, 0, stream>>>(w4u, Wzr_t + 3145728l + 2048,  1024, 1024, 3072);
    transpose_cvt<<<dim3(32, 64), tb, 0, stream>>>(w5w, W5_t,                     2048, 1024, 3072);
    transpose_cvt<<<dim3(32, 32), tb, 0, stream>>>(w5u, W5_t + 2048,              1024, 1024, 3072);
    transpose_cvt<<<dim3(32, 64), tb, 0, stream>>>(fcw, fcw_t,                    2048, 1024, 2048);
    init_nodes_k<<<dim3(64, 32), tb, 0, stream>>>(lfw, nodesT, nodes, avn, ninit);

    // ---- GGNN time steps ----
    for (int t = 0; t < 3; ++t) {
        // avn[:,0:1024] = in@nodes ; avn[:,1024:2048] = inT@nodes  (fused, 256 blocks)
        gemm_p3<true ><<<dim3( 8, 16, 2), tb, 0, stream>>>(inM_bf, inMT_bf, nodesT,
            avn, 2048, 2048, 2048, 3072, 0, 1024);
        // zpre|rpre = avn @ [w3|w4]  (K=3072, 256 blocks)
        gemm_p3<false><<<dim3(16, 16, 1), tb, 0, stream>>>(avn, avn, Wzr_t,
            zrbuf, 3072, 3072, 3072, 2048, 0, 0);
        gates_zr_k<<<8192, tb, 0, stream>>>(zrbuf, nodes, zv, avn);
        // hpre(z) = avn[:, z*1536:] @ W5_t[:, z*1536:]  (split-K x2, 256 blocks)
        gemm_p3<false><<<dim3( 8, 16, 2), tb, 0, stream>>>(avn, avn, W5_t,
            hpre, 1536, 3072, 3072, 1024, 1536, 2097152);
        update_nodes_k<<<dim3(32, 64), tb, 0, stream>>>(nodes, zv, hpre, avn, ninit, nodesT);
    }

    // step_out partials = [nodes|init] @ fc_out_w  (split-K x2, 256 blocks)
    gemm_p3<false><<<dim3( 8, 16, 2), tb, 0, stream>>>(ninit, ninit, fcw_t,
        sop, 1024, 2048, 2048, 1024, 1024, 2097152);
    bias_l2<<<1024, tb, 0, stream>>>(sop, fcb, so_bf, partials);
    reduce_final<<<1, tb, 0, stream>>>(partials, out + (long)B * N);
    // output = x @ step_out^T  (1024 blocks)
    gemm_p3<false><<<dim3(16, 64, 1), tb, 0, stream>>>(x_bf, x_bf, so_bf,
        out, 1024, 1024, 1024, 2048, 0, 0);
}

// Round 4
// 480.257 us; speedup vs baseline: 11.4370x; 1.1509x over previous
//
#include <hip/hip_runtime.h>
#include <hip/hip_bf16.h>
#include <stdint.h>

// KGTN round 4: occupancy-first 64x128 bf16 MFMA GEMM.
// BM=64 BN=128 BK=64, 2 LDS buffers (48 KiB) -> 3 blocks/CU possible;
// per K-step: SYNC(vmcnt0+barrier) -> STAGE(t+1, other buf) -> COMPUTE(t).
// Stage-after-barrier makes the 2-buffer swap race-free; tile t+1 in flight
// one compute period (distance-1). T2 XOR swizzle (pre-swizzled source
// granule + swizzled read granule), T5 setprio. Grids: GGNN GEMMs 512
// blocks (2/CU), final 2048 blocks (3/CU).

typedef __attribute__((ext_vector_type(8))) short bf16x8;
typedef __attribute__((ext_vector_type(4))) float f32x4;
typedef __attribute__((ext_vector_type(4))) ushort u16x4;

typedef __attribute__((address_space(3))) void lds_void;
typedef const __attribute__((address_space(1))) void gbl_void;

__device__ __forceinline__ ushort f2b(float v) {
    union { float f; uint32_t u; } c; c.f = v;
    uint32_t u = c.u + 0x7FFFu + ((c.u >> 16) & 1u);   // RNE; inputs finite
    return (ushort)(u >> 16);
}

// C[M,N] (+ z-variants) = A[M,K] @ B[K,N]; A row-major bf16 (lda),
// Bt = B^T [N,K] row-major bf16 (ldb). Grid: x=N/128, y=M/64, z in {1,2}.
// z selects A0/A1, offsets A,Bt by z*aKoff (elems along K), C by z*cOff.
template <bool OUT_BF16>
__global__ __launch_bounds__(256) void gemm_occ(
    const ushort* __restrict__ A0, const ushort* __restrict__ A1,
    const ushort* __restrict__ Bt, void* __restrict__ Cv,
    int K, int lda, int ldb, int ldc, long aKoff, long cOff)
{
    __shared__ ushort As[2 * 4096];    // 2 x 64x64 bf16  (16 KiB)
    __shared__ ushort Bs[2 * 8192];    // 2 x 128x64 bf16 (32 KiB)
    const int tid  = threadIdx.x;
    const int lane = tid & 63;
    const int wave = tid >> 6;
    const int wr = (wave >> 1) * 32;               // 2 row bands of 32
    const int wc = (wave & 1) * 64;                // 2 col bands of 64
    const long bm = (long)blockIdx.y * 64;
    const long bn = (long)blockIdx.x * 128;
    const int z  = blockIdx.z;

    const ushort* A  = (z ? A1 : A0) + (long)z * aKoff;
    const ushort* Bp = Bt + (long)z * aKoff;

    const int l15  = lane & 15;
    const int kg   = lane >> 4;                    // 0..3
    const int srow = lane >> 3;                    // 0..7
    const int gsw  = ((lane & 7) ^ srow) & 7;      // pre-swizzled src granule

    f32x4 acc[2][4] = {};

    // stage one BK=64 K-tile (A: 2 slots/wave, B: 4 slots/wave; 6 loads)
    auto STAGE = [&](int k0, int buf) {
        #pragma unroll
        for (int p = 0; p < 2; ++p) {
            const int slot = wave * 2 + p;         // 8 slots x 8 rows = 64
            const int row  = slot * 8 + srow;
            const ushort* ga = A + (bm + row) * (long)lda + (k0 + gsw * 8);
            __builtin_amdgcn_global_load_lds((gbl_void*)ga,
                (lds_void*)(As + buf * 4096 + slot * 512), 16, 0, 0);
        }
        #pragma unroll
        for (int p = 0; p < 4; ++p) {
            const int slot = wave * 4 + p;         // 16 slots x 8 rows = 128
            const int row  = slot * 8 + srow;
            const ushort* gb = Bp + (bn + row) * (long)ldb + (k0 + gsw * 8);
            __builtin_amdgcn_global_load_lds((gbl_void*)gb,
                (lds_void*)(Bs + buf * 8192 + slot * 512), 16, 0, 0);
        }
    };

    auto COMPUTE = [&](int buf) {
        const ushort* as = As + buf * 4096;
        const ushort* bs = Bs + buf * 8192;
        #pragma unroll
        for (int kk = 0; kk < 2; ++kk) {
            const int ph = (((kk * 4 + kg) ^ (lane & 7)) & 7) * 8;
            bf16x8 af[2], bv[4];
            #pragma unroll
            for (int m = 0; m < 2; ++m)
                af[m] = *(const bf16x8*)(as + (wr + m * 16 + l15) * 64 + ph);
            #pragma unroll
            for (int n = 0; n < 4; ++n)
                bv[n] = *(const bf16x8*)(bs + (wc + n * 16 + l15) * 64 + ph);
            __builtin_amdgcn_s_setprio(1);
            #pragma unroll
            for (int m = 0; m < 2; ++m)
                #pragma unroll
                for (int n = 0; n < 4; ++n)
                    acc[m][n] = __builtin_amdgcn_mfma_f32_16x16x32_bf16(
                        af[m], bv[n], acc[m][n], 0, 0, 0);
            __builtin_amdgcn_s_setprio(0);
        }
    };

#define SYNC()                                              \
    __builtin_amdgcn_sched_barrier(0);                      \
    asm volatile("s_waitcnt vmcnt(0)" ::: "memory");        \
    __builtin_amdgcn_s_barrier();                           \
    __builtin_amdgcn_sched_barrier(0)

    const int T = K >> 6;                  // >= 16 for all our shapes
    STAGE(0, 0);
    for (int t = 0; t < T; ++t) {
        SYNC();                            // tile t landed; compute t-1 done
        if (t + 1 < T) STAGE((t + 1) * 64, (t + 1) & 1);
        COMPUTE(t & 1);
    }
#undef SYNC

    // C/D layout: col = lane&15, row = (lane>>4)*4 + reg   [m89-verified]
    const int cr0 = (lane >> 4) * 4;
    #pragma unroll
    for (int m = 0; m < 2; ++m) {
        #pragma unroll
        for (int j = 0; j < 4; ++j) {
            const long r = bm + wr + m * 16 + cr0 + j;
            if (OUT_BF16) {
                ushort* C = (ushort*)Cv + (long)z * cOff;
                #pragma unroll
                for (int n = 0; n < 4; ++n)
                    C[r * (long)ldc + bn + wc + n * 16 + l15] = f2b(acc[m][n][j]);
            } else {
                float* C = (float*)Cv + (long)z * cOff;
                #pragma unroll
                for (int n = 0; n < 4; ++n)
                    C[r * (long)ldc + bn + wc + n * 16 + l15] = acc[m][n][j];
            }
        }
    }
}

// fp32 -> bf16 elementwise, 4 elems/thread. n4 = total/4.
__global__ __launch_bounds__(256) void cvt_bf16_k(const float* __restrict__ src,
                                                  ushort* __restrict__ dst, long n4) {
    long i = (long)blockIdx.x * 256 + threadIdx.x;
    if (i >= n4) return;
    f32x4 v = *(const f32x4*)(src + i * 4);
    u16x4 o;
    #pragma unroll
    for (int j = 0; j < 4; ++j) o[j] = f2b(v[j]);
    *(u16x4*)(dst + i * 4) = o;
}

// dst[c*dld + r] = bf16(src[r*C + c]). Grid (C/32, R/32), block 256.
__global__ __launch_bounds__(256) void transpose_cvt(const float* __restrict__ src,
                                                     ushort* __restrict__ dst,
                                                     int R, int C, int dld) {
    __shared__ float t[32][33];
    const int c0 = blockIdx.x * 32, r0 = blockIdx.y * 32;
    const int tx = threadIdx.x & 31, ty = threadIdx.x >> 5;
    #pragma unroll
    for (int i = 0; i < 32; i += 8)
        t[ty + i][tx] = src[(long)(r0 + ty + i) * C + c0 + tx];
    __syncthreads();
    #pragma unroll
    for (int i = 0; i < 32; i += 8)
        dst[(long)(c0 + ty + i) * dld + r0 + tx] = f2b(t[tx][ty + i]);
}

// From lfw [1024(h), 2048(N)]: nodesT_bf[h][N], nodes f32 [N][h],
// nodes_bf -> avn cols 2048:3072, init_bf -> ninit cols 1024:2048.
__global__ __launch_bounds__(256) void init_nodes_k(const float* __restrict__ lfw,
        ushort* __restrict__ nodesT, float* __restrict__ nodes,
        ushort* __restrict__ avn, ushort* __restrict__ ninit) {
    __shared__ float t[32][33];
    const int n0 = blockIdx.x * 32, h0 = blockIdx.y * 32;
    const int tx = threadIdx.x & 31, ty = threadIdx.x >> 5;
    #pragma unroll
    for (int i = 0; i < 32; i += 8) {
        float v = lfw[(long)(h0 + ty + i) * 2048 + n0 + tx];
        nodesT[(long)(h0 + ty + i) * 2048 + n0 + tx] = f2b(v);
        t[ty + i][tx] = v;
    }
    __syncthreads();
    #pragma unroll
    for (int i = 0; i < 32; i += 8) {
        const int n = n0 + ty + i, hh = h0 + tx;
        float v = t[tx][ty + i];
        nodes[(long)n * 1024 + hh] = v;
        ushort b = f2b(v);
        avn[(long)n * 3072 + 2048 + hh] = b;
        ninit[(long)n * 2048 + 1024 + hh] = b;
    }
}

// zv = sigmoid(zpre); rn_bf = bf16(sigmoid(rpre)*nodes) -> avn cols 2048:3072
__global__ __launch_bounds__(256) void gates_zr_k(const float* __restrict__ zr,
        const float* __restrict__ nodes, float* __restrict__ zv,
        ushort* __restrict__ avn) {
    const long i = (long)blockIdx.x * 256 + threadIdx.x;   // over [2048,1024]
    const int r = (int)(i >> 10), c = (int)(i & 1023);
    const float zp = zr[(long)r * 2048 + c];
    const float rp = zr[(long)r * 2048 + 1024 + c];
    const float z = 1.f / (1.f + __expf(-zp));
    zv[i] = z;
    const float rn = (1.f / (1.f + __expf(-rp))) * nodes[i];
    avn[(long)r * 3072 + 2048 + c] = f2b(rn);
}

// nodes = (1-z)*nodes + z*tanh(hp0+hp1); emit nodes_bf + transposed copy.
__global__ __launch_bounds__(256) void update_nodes_k(float* __restrict__ nodes,
        const float* __restrict__ zv, const float* __restrict__ hp,
        ushort* __restrict__ avn, ushort* __restrict__ ninit,
        ushort* __restrict__ nodesT) {
    __shared__ float t[32][33];
    const int c0 = blockIdx.x * 32, r0 = blockIdx.y * 32;
    const int tx = threadIdx.x & 31, ty = threadIdx.x >> 5;
    #pragma unroll
    for (int i = 0; i < 32; i += 8) {
        const int r = r0 + ty + i, c = c0 + tx;
        const long idx = (long)r * 1024 + c;
        const float z = zv[idx];
        const float hsum = hp[idx] + hp[idx + 2097152];
        const float nn = (1.f - z) * nodes[idx] + z * tanhf(hsum);
        nodes[idx] = nn;
        const ushort b = f2b(nn);
        avn[(long)r * 3072 + 2048 + c] = b;
        ninit[(long)r * 2048 + c] = b;
        t[ty + i][tx] = nn;
    }
    __syncthreads();
    #pragma unroll
    for (int i = 0; i < 32; i += 8)
        nodesT[(long)(c0 + ty + i) * 2048 + r0 + tx] = f2b(t[tx][ty + i]);
}

// v = sop0+sop1+bias; so_bf = bf16(v); partial sums of v^2. 1024 blocks.
__global__ __launch_bounds__(256) void bias_l2(const float* __restrict__ s,
        const float* __restrict__ bias, ushort* __restrict__ so_bf,
        float* __restrict__ partials) {
    __shared__ float red[256];
    const int tid = threadIdx.x;
    const long base = (long)blockIdx.x * 2048;
    float sum = 0.f;
    #pragma unroll
    for (int it = 0; it < 8; ++it) {
        const long i = base + tid + it * 256;
        const float v = s[i] + s[i + 2097152] + bias[i & 1023];
        so_bf[i] = f2b(v);
        sum += v * v;
    }
    red[tid] = sum;
    __syncthreads();
    #pragma unroll
    for (int w = 128; w > 0; w >>= 1) {
        if (tid < w) red[tid] += red[tid + w];
        __syncthreads();
    }
    if (tid == 0) partials[blockIdx.x] = red[0];
}

__global__ __launch_bounds__(256) void reduce_final(const float* __restrict__ partials,
                                                    float* __restrict__ out) {
    __shared__ float red[256];
    const int tid = threadIdx.x;
    red[tid] = partials[tid] + partials[tid + 256] + partials[tid + 512] + partials[tid + 768];
    __syncthreads();
    #pragma unroll
    for (int w = 128; w > 0; w >>= 1) {
        if (tid < w) red[tid] += red[tid + w];
        __syncthreads();
    }
    if (tid == 0) out[0] = red[0];
}

extern "C" void kernel_launch(void* const* d_in, const int* in_sizes, int n_in,
                              void* d_out, int out_size, void* d_ws, size_t ws_size,
                              hipStream_t stream) {
    const float* x   = (const float*)d_in[0];   // [8192,1024]
    const float* lfw = (const float*)d_in[1];   // [1024,2048]
    const float* inM = (const float*)d_in[2];   // [2048,2048]
    const float* w3w = (const float*)d_in[3];
    const float* w3u = (const float*)d_in[4];
    const float* w4w = (const float*)d_in[5];
    const float* w4u = (const float*)d_in[6];
    const float* w5w = (const float*)d_in[7];
    const float* w5u = (const float*)d_in[8];
    const float* fcw = (const float*)d_in[9];
    const float* fcb = (const float*)d_in[10];
    float* out = (float*)d_out;

    const int B = 8192, N = 2048;
    const long NH = 2097152;

    // d_out front as fp32 scratch (dead before final GEMM rewrites d_out):
    float* zrbuf = out;                 // [2048,2048]
    float* hpre  = out + 4194304l;      // 2x [2048,1024]
    float* sop   = out + 8388608l;      // 2x [2048,1024]

    char* p = (char*)d_ws;
    auto alloc = [&](size_t bytes) {
        char* r = p; p += (bytes + 255) & ~(size_t)255; return r;
    };
    float*  nodes    = (float*)alloc(NH * 4);
    float*  zv       = (float*)alloc(NH * 4);
    float*  partials = (float*)alloc(1024 * 4);
    ushort* avn      = (ushort*)alloc(6291456ull * 2);  // [2048,3072]
    ushort* nodesT   = (ushort*)alloc(NH * 2);          // [1024,2048]
    ushort* ninit    = (ushort*)alloc(4194304ull * 2);  // [2048,2048]
    ushort* inM_bf   = (ushort*)alloc(4194304ull * 2);
    ushort* inMT_bf  = (ushort*)alloc(4194304ull * 2);
    ushort* Wzr_t    = (ushort*)alloc(6291456ull * 2);  // [2048,3072]
    ushort* W5_t     = (ushort*)alloc(3145728ull * 2);  // [1024,3072]
    ushort* fcw_t    = (ushort*)alloc(NH * 2);          // [1024,2048]
    ushort* x_bf     = (ushort*)alloc(8388608ull * 2);  // [8192,1024]
    ushort* so_bf    = (ushort*)alloc(NH * 2);          // [2048,1024]

    const dim3 tb(256);

    // ---- prep ----
    cvt_bf16_k<<<8192, tb, 0, stream>>>(x, x_bf, 2097152);
    cvt_bf16_k<<<4096, tb, 0, stream>>>(inM, inM_bf, 1048576);
    transpose_cvt<<<dim3(64, 64), tb, 0, stream>>>(inM, inMT_bf, 2048, 2048, 2048);
    transpose_cvt<<<dim3(32, 64), tb, 0, stream>>>(w3w, Wzr_t,                    2048, 1024, 3072);
    transpose_cvt<<<dim3(32, 32), tb, 0, stream>>>(w3u, Wzr_t + 2048,             1024, 1024, 3072);
    transpose_cvt<<<dim3(32, 64), tb, 0, stream>>>(w4w, Wzr_t + 3145728l,         2048, 1024, 3072);
    transpose_cvt<<<dim3(32, 32), tb, 0, stream>>>(w4u, Wzr_t + 3145728l + 2048,  1024, 1024, 3072);
    transpose_cvt<<<dim3(32, 64), tb, 0, stream>>>(w5w, W5_t,                     2048, 1024, 3072);
    transpose_cvt<<<dim3(32, 32), tb, 0, stream>>>(w5u, W5_t + 2048,              1024, 1024, 3072);
    transpose_cvt<<<dim3(32, 64), tb, 0, stream>>>(fcw, fcw_t,                    2048, 1024, 2048);
    init_nodes_k<<<dim3(64, 32), tb, 0, stream>>>(lfw, nodesT, nodes, avn, ninit);

    // ---- GGNN time steps ----
    for (int t = 0; t < 3; ++t) {
        // avn[:,0:1024] = in@nodes ; avn[:,1024:2048] = inT@nodes  (512 blocks)
        gemm_occ<true ><<<dim3( 8, 32, 2), tb, 0, stream>>>(inM_bf, inMT_bf, nodesT,
            avn, 2048, 2048, 2048, 3072, 0, 1024);
        // zpre|rpre = avn @ [w3|w4]  (K=3072, 512 blocks)
        gemm_occ<false><<<dim3(16, 32, 1), tb, 0, stream>>>(avn, avn, Wzr_t,
            zrbuf, 3072, 3072, 3072, 2048, 0, 0);
        gates_zr_k<<<8192, tb, 0, stream>>>(zrbuf, nodes, zv, avn);
        // hpre(z) = avn[:, z*1536:] @ W5_t[:, z*1536:]  (split-K x2, 512 blocks)
        gemm_occ<false><<<dim3( 8, 32, 2), tb, 0, stream>>>(avn, avn, W5_t,
            hpre, 1536, 3072, 3072, 1024, 1536, 2097152);
        update_nodes_k<<<dim3(32, 64), tb, 0, stream>>>(nodes, zv, hpre, avn, ninit, nodesT);
    }

    // step_out partials = [nodes|init] @ fc_out_w  (split-K x2, 512 blocks)
    gemm_occ<false><<<dim3( 8, 32, 2), tb, 0, stream>>>(ninit, ninit, fcw_t,
        sop, 1024, 2048, 2048, 1024, 1024, 2097152);
    bias_l2<<<1024, tb, 0, stream>>>(sop, fcb, so_bf, partials);
    reduce_final<<<1, tb, 0, stream>>>(partials, out + (long)B * N);
    // output = x @ step_out^T  (2048 blocks)
    gemm_occ<false><<<dim3(16, 128, 1), tb, 0, stream>>>(x_bf, x_bf, so_bf,
        out, 1024, 1024, 1024, 2048, 0, 0);
}

// Round 5
// 462.111 us; speedup vs baseline: 11.8861x; 1.0393x over previous
//
#include <hip/hip_runtime.h>
#include <hip/hip_bf16.h>
#include <stdint.h>

// KGTN round 5: 64x128 bf16 MFMA GEMM, depth-2 counted-vmcnt pipeline.
// BM=64 BN=128 BK=64, THREE LDS buffers (72 KiB -> still 2 blocks/CU),
// steady-state s_waitcnt vmcnt(6) (= 1 tile of 6 loads/wave in flight past
// the wait; never 0 in main loop). Per K-step: SYNC(6) -> STAGE(t+2) ->
// COMPUTE(t). Epilogue SYNC(6), SYNC(0). T1 bijective XCD swizzle on the
// linearized block id (all grids %8==0). T2 XOR swizzle + T5 setprio kept.

typedef __attribute__((ext_vector_type(8))) short bf16x8;
typedef __attribute__((ext_vector_type(4))) float f32x4;
typedef __attribute__((ext_vector_type(4))) ushort u16x4;

typedef __attribute__((address_space(3))) void lds_void;
typedef const __attribute__((address_space(1))) void gbl_void;

__device__ __forceinline__ ushort f2b(float v) {
    union { float f; uint32_t u; } c; c.f = v;
    uint32_t u = c.u + 0x7FFFu + ((c.u >> 16) & 1u);   // RNE; inputs finite
    return (ushort)(u >> 16);
}

// C[M,N] (+ z-variants) = A[M,K] @ B[K,N]; A row-major bf16 (lda),
// Bt = B^T [N,K] row-major bf16 (ldb). Grid: x=N/128, y=M/64, z in {1,2}.
// z selects A0/A1, offsets A,Bt by z*aKoff (elems along K), C by z*cOff.
// Requires gridDim.x*gridDim.y % 8 == 0 (XCD swizzle) and K % 128 == 0.
template <bool OUT_BF16>
__global__ __launch_bounds__(256) void gemm_d2(
    const ushort* __restrict__ A0, const ushort* __restrict__ A1,
    const ushort* __restrict__ Bt, void* __restrict__ Cv,
    int K, int lda, int ldb, int ldc, long aKoff, long cOff)
{
    __shared__ ushort As[3 * 4096];    // 3 x 64x64 bf16  (24 KiB)
    __shared__ ushort Bs[3 * 8192];    // 3 x 128x64 bf16 (48 KiB)
    const int tid  = threadIdx.x;
    const int lane = tid & 63;
    const int wave = tid >> 6;
    const int wr = (wave >> 1) * 32;               // 2 row bands of 32
    const int wc = (wave & 1) * 64;                // 2 col bands of 64

    // T1: bijective XCD-chunked remap of linearized (y,x) id. nwg%8==0.
    const int gx  = gridDim.x;
    const int nwg = gx * gridDim.y;
    int bid = blockIdx.y * gx + blockIdx.x;
    bid = (bid & 7) * (nwg >> 3) + (bid >> 3);
    const long bm = (long)(bid / gx) * 64;
    const long bn = (long)(bid % gx) * 128;
    const int z  = blockIdx.z;

    const ushort* A  = (z ? A1 : A0) + (long)z * aKoff;
    const ushort* Bp = Bt + (long)z * aKoff;

    const int l15  = lane & 15;
    const int kg   = lane >> 4;                    // 0..3
    const int srow = lane >> 3;                    // 0..7
    const int gsw  = ((lane & 7) ^ srow) & 7;      // pre-swizzled src granule

    f32x4 acc[2][4] = {};

    // stage one BK=64 K-tile (A: 2 slots/wave, B: 4 slots/wave; 6 loads/wave)
    auto STAGE = [&](int k0, int buf) {
        #pragma unroll
        for (int p = 0; p < 2; ++p) {
            const int slot = wave * 2 + p;         // 8 slots x 8 rows = 64
            const int row  = slot * 8 + srow;
            const ushort* ga = A + (bm + row) * (long)lda + (k0 + gsw * 8);
            __builtin_amdgcn_global_load_lds((gbl_void*)ga,
                (lds_void*)(As + buf * 4096 + slot * 512), 16, 0, 0);
        }
        #pragma unroll
        for (int p = 0; p < 4; ++p) {
            const int slot = wave * 4 + p;         // 16 slots x 8 rows = 128
            const int row  = slot * 8 + srow;
            const ushort* gb = Bp + (bn + row) * (long)ldb + (k0 + gsw * 8);
            __builtin_amdgcn_global_load_lds((gbl_void*)gb,
                (lds_void*)(Bs + buf * 8192 + slot * 512), 16, 0, 0);
        }
    };

    auto COMPUTE = [&](int buf) {
        const ushort* as = As + buf * 4096;
        const ushort* bs = Bs + buf * 8192;
        #pragma unroll
        for (int kk = 0; kk < 2; ++kk) {
            const int ph = (((kk * 4 + kg) ^ (lane & 7)) & 7) * 8;
            bf16x8 af[2], bv[4];
            #pragma unroll
            for (int m = 0; m < 2; ++m)
                af[m] = *(const bf16x8*)(as + (wr + m * 16 + l15) * 64 + ph);
            #pragma unroll
            for (int n = 0; n < 4; ++n)
                bv[n] = *(const bf16x8*)(bs + (wc + n * 16 + l15) * 64 + ph);
            __builtin_amdgcn_s_setprio(1);
            #pragma unroll
            for (int m = 0; m < 2; ++m)
                #pragma unroll
                for (int n = 0; n < 4; ++n)
                    acc[m][n] = __builtin_amdgcn_mfma_f32_16x16x32_bf16(
                        af[m], bv[n], acc[m][n], 0, 0, 0);
            __builtin_amdgcn_s_setprio(0);
        }
    };

#define SYNC(VM)                                            \
    __builtin_amdgcn_sched_barrier(0);                      \
    asm volatile("s_waitcnt vmcnt(" #VM ")" ::: "memory");  \
    __builtin_amdgcn_s_barrier();                           \
    __builtin_amdgcn_sched_barrier(0)

    const int T = K >> 6;                  // >= 16 for all our shapes
    STAGE(0, 0); STAGE(64, 1);
    int cb = 0;                            // compute buffer
    for (int t = 0; t < T - 2; ++t) {
        SYNC(6);                           // tile t landed (t, t+1 were out)
        int sbuf = cb + 2; if (sbuf >= 3) sbuf -= 3;
        STAGE((t + 2) * 64, sbuf);         // overwrites buf of tile t-1
        COMPUTE(cb);
        if (++cb == 3) cb = 0;
    }
    SYNC(6); COMPUTE(cb); if (++cb == 3) cb = 0;   // t = T-2
    SYNC(0); COMPUTE(cb);                          // t = T-1
#undef SYNC

    // C/D layout: col = lane&15, row = (lane>>4)*4 + reg   [m89-verified]
    const int cr0 = (lane >> 4) * 4;
    #pragma unroll
    for (int m = 0; m < 2; ++m) {
        #pragma unroll
        for (int j = 0; j < 4; ++j) {
            const long r = bm + wr + m * 16 + cr0 + j;
            if (OUT_BF16) {
                ushort* C = (ushort*)Cv + (long)z * cOff;
                #pragma unroll
                for (int n = 0; n < 4; ++n)
                    C[r * (long)ldc + bn + wc + n * 16 + l15] = f2b(acc[m][n][j]);
            } else {
                float* C = (float*)Cv + (long)z * cOff;
                #pragma unroll
                for (int n = 0; n < 4; ++n)
                    C[r * (long)ldc + bn + wc + n * 16 + l15] = acc[m][n][j];
            }
        }
    }
}

// fp32 -> bf16 elementwise, 4 elems/thread. n4 = total/4.
__global__ __launch_bounds__(256) void cvt_bf16_k(const float* __restrict__ src,
                                                  ushort* __restrict__ dst, long n4) {
    long i = (long)blockIdx.x * 256 + threadIdx.x;
    if (i >= n4) return;
    f32x4 v = *(const f32x4*)(src + i * 4);
    u16x4 o;
    #pragma unroll
    for (int j = 0; j < 4; ++j) o[j] = f2b(v[j]);
    *(u16x4*)(dst + i * 4) = o;
}

// dst[c*dld + r] = bf16(src[r*C + c]). Grid (C/32, R/32), block 256.
__global__ __launch_bounds__(256) void transpose_cvt(const float* __restrict__ src,
                                                     ushort* __restrict__ dst,
                                                     int R, int C, int dld) {
    __shared__ float t[32][33];
    const int c0 = blockIdx.x * 32, r0 = blockIdx.y * 32;
    const int tx = threadIdx.x & 31, ty = threadIdx.x >> 5;
    #pragma unroll
    for (int i = 0; i < 32; i += 8)
        t[ty + i][tx] = src[(long)(r0 + ty + i) * C + c0 + tx];
    __syncthreads();
    #pragma unroll
    for (int i = 0; i < 32; i += 8)
        dst[(long)(c0 + ty + i) * dld + r0 + tx] = f2b(t[tx][ty + i]);
}

// From lfw [1024(h), 2048(N)]: nodesT_bf[h][N], nodes f32 [N][h],
// nodes_bf -> avn cols 2048:3072, init_bf -> ninit cols 1024:2048.
__global__ __launch_bounds__(256) void init_nodes_k(const float* __restrict__ lfw,
        ushort* __restrict__ nodesT, float* __restrict__ nodes,
        ushort* __restrict__ avn, ushort* __restrict__ ninit) {
    __shared__ float t[32][33];
    const int n0 = blockIdx.x * 32, h0 = blockIdx.y * 32;
    const int tx = threadIdx.x & 31, ty = threadIdx.x >> 5;
    #pragma unroll
    for (int i = 0; i < 32; i += 8) {
        float v = lfw[(long)(h0 + ty + i) * 2048 + n0 + tx];
        nodesT[(long)(h0 + ty + i) * 2048 + n0 + tx] = f2b(v);
        t[ty + i][tx] = v;
    }
    __syncthreads();
    #pragma unroll
    for (int i = 0; i < 32; i += 8) {
        const int n = n0 + ty + i, hh = h0 + tx;
        float v = t[tx][ty + i];
        nodes[(long)n * 1024 + hh] = v;
        ushort b = f2b(v);
        avn[(long)n * 3072 + 2048 + hh] = b;
        ninit[(long)n * 2048 + 1024 + hh] = b;
    }
}

// zv = sigmoid(zpre); rn_bf = bf16(sigmoid(rpre)*nodes) -> avn cols 2048:3072
__global__ __launch_bounds__(256) void gates_zr_k(const float* __restrict__ zr,
        const float* __restrict__ nodes, float* __restrict__ zv,
        ushort* __restrict__ avn) {
    const long i = (long)blockIdx.x * 256 + threadIdx.x;   // over [2048,1024]
    const int r = (int)(i >> 10), c = (int)(i & 1023);
    const float zp = zr[(long)r * 2048 + c];
    const float rp = zr[(long)r * 2048 + 1024 + c];
    const float z = 1.f / (1.f + __expf(-zp));
    zv[i] = z;
    const float rn = (1.f / (1.f + __expf(-rp))) * nodes[i];
    avn[(long)r * 3072 + 2048 + c] = f2b(rn);
}

// nodes = (1-z)*nodes + z*tanh(hp0+hp1); emit nodes_bf + transposed copy.
__global__ __launch_bounds__(256) void update_nodes_k(float* __restrict__ nodes,
        const float* __restrict__ zv, const float* __restrict__ hp,
        ushort* __restrict__ avn, ushort* __restrict__ ninit,
        ushort* __restrict__ nodesT) {
    __shared__ float t[32][33];
    const int c0 = blockIdx.x * 32, r0 = blockIdx.y * 32;
    const int tx = threadIdx.x & 31, ty = threadIdx.x >> 5;
    #pragma unroll
    for (int i = 0; i < 32; i += 8) {
        const int r = r0 + ty + i, c = c0 + tx;
        const long idx = (long)r * 1024 + c;
        const float z = zv[idx];
        const float hsum = hp[idx] + hp[idx + 2097152];
        const float nn = (1.f - z) * nodes[idx] + z * tanhf(hsum);
        nodes[idx] = nn;
        const ushort b = f2b(nn);
        avn[(long)r * 3072 + 2048 + c] = b;
        ninit[(long)r * 2048 + c] = b;
        t[ty + i][tx] = nn;
    }
    __syncthreads();
    #pragma unroll
    for (int i = 0; i < 32; i += 8)
        nodesT[(long)(c0 + ty + i) * 2048 + r0 + tx] = f2b(t[tx][ty + i]);
}

// v = sop0+sop1+bias; so_bf = bf16(v); partial sums of v^2. 1024 blocks.
__global__ __launch_bounds__(256) void bias_l2(const float* __restrict__ s,
        const float* __restrict__ bias, ushort* __restrict__ so_bf,
        float* __restrict__ partials) {
    __shared__ float red[256];
    const int tid = threadIdx.x;
    const long base = (long)blockIdx.x * 2048;
    float sum = 0.f;
    #pragma unroll
    for (int it = 0; it < 8; ++it) {
        const long i = base + tid + it * 256;
        const float v = s[i] + s[i + 2097152] + bias[i & 1023];
        so_bf[i] = f2b(v);
        sum += v * v;
    }
    red[tid] = sum;
    __syncthreads();
    #pragma unroll
    for (int w = 128; w > 0; w >>= 1) {
        if (tid < w) red[tid] += red[tid + w];
        __syncthreads();
    }
    if (tid == 0) partials[blockIdx.x] = red[0];
}

__global__ __launch_bounds__(256) void reduce_final(const float* __restrict__ partials,
                                                    float* __restrict__ out) {
    __shared__ float red[256];
    const int tid = threadIdx.x;
    red[tid] = partials[tid] + partials[tid + 256] + partials[tid + 512] + partials[tid + 768];
    __syncthreads();
    #pragma unroll
    for (int w = 128; w > 0; w >>= 1) {
        if (tid < w) red[tid] += red[tid + w];
        __syncthreads();
    }
    if (tid == 0) out[0] = red[0];
}

extern "C" void kernel_launch(void* const* d_in, const int* in_sizes, int n_in,
                              void* d_out, int out_size, void* d_ws, size_t ws_size,
                              hipStream_t stream) {
    const float* x   = (const float*)d_in[0];   // [8192,1024]
    const float* lfw = (const float*)d_in[1];   // [1024,2048]
    const float* inM = (const float*)d_in[2];   // [2048,2048]
    const float* w3w = (const float*)d_in[3];
    const float* w3u = (const float*)d_in[4];
    const float* w4w = (const float*)d_in[5];
    const float* w4u = (const float*)d_in[6];
    const float* w5w = (const float*)d_in[7];
    const float* w5u = (const float*)d_in[8];
    const float* fcw = (const float*)d_in[9];
    const float* fcb = (const float*)d_in[10];
    float* out = (float*)d_out;

    const int B = 8192, N = 2048;
    const long NH = 2097152;

    // d_out front as fp32 scratch (dead before final GEMM rewrites d_out):
    float* zrbuf = out;                 // [2048,2048]
    float* hpre  = out + 4194304l;      // 2x [2048,1024]
    float* sop   = out + 8388608l;      // 2x [2048,1024]

    char* p = (char*)d_ws;
    auto alloc = [&](size_t bytes) {
        char* r = p; p += (bytes + 255) & ~(size_t)255; return r;
    };
    float*  nodes    = (float*)alloc(NH * 4);
    float*  zv       = (float*)alloc(NH * 4);
    float*  partials = (float*)alloc(1024 * 4);
    ushort* avn      = (ushort*)alloc(6291456ull * 2);  // [2048,3072]
    ushort* nodesT   = (ushort*)alloc(NH * 2);          // [1024,2048]
    ushort* ninit    = (ushort*)alloc(4194304ull * 2);  // [2048,2048]
    ushort* inM_bf   = (ushort*)alloc(4194304ull * 2);
    ushort* inMT_bf  = (ushort*)alloc(4194304ull * 2);
    ushort* Wzr_t    = (ushort*)alloc(6291456ull * 2);  // [2048,3072]
    ushort* W5_t     = (ushort*)alloc(3145728ull * 2);  // [1024,3072]
    ushort* fcw_t    = (ushort*)alloc(NH * 2);          // [1024,2048]
    ushort* x_bf     = (ushort*)alloc(8388608ull * 2);  // [8192,1024]
    ushort* so_bf    = (ushort*)alloc(NH * 2);          // [2048,1024]

    const dim3 tb(256);

    // ---- prep ----
    cvt_bf16_k<<<8192, tb, 0, stream>>>(x, x_bf, 2097152);
    cvt_bf16_k<<<4096, tb, 0, stream>>>(inM, inM_bf, 1048576);
    transpose_cvt<<<dim3(64, 64), tb, 0, stream>>>(inM, inMT_bf, 2048, 2048, 2048);
    transpose_cvt<<<dim3(32, 64), tb, 0, stream>>>(w3w, Wzr_t,                    2048, 1024, 3072);
    transpose_cvt<<<dim3(32, 32), tb, 0, stream>>>(w3u, Wzr_t + 2048,             1024, 1024, 3072);
    transpose_cvt<<<dim3(32, 64), tb, 0, stream>>>(w4w, Wzr_t + 3145728l,         2048, 1024, 3072);
    transpose_cvt<<<dim3(32, 32), tb, 0, stream>>>(w4u, Wzr_t + 3145728l + 2048,  1024, 1024, 3072);
    transpose_cvt<<<dim3(32, 64), tb, 0, stream>>>(w5w, W5_t,                     2048, 1024, 3072);
    transpose_cvt<<<dim3(32, 32), tb, 0, stream>>>(w5u, W5_t + 2048,              1024, 1024, 3072);
    transpose_cvt<<<dim3(32, 64), tb, 0, stream>>>(fcw, fcw_t,                    2048, 1024, 2048);
    init_nodes_k<<<dim3(64, 32), tb, 0, stream>>>(lfw, nodesT, nodes, avn, ninit);

    // ---- GGNN time steps ----
    for (int t = 0; t < 3; ++t) {
        // avn[:,0:1024] = in@nodes ; avn[:,1024:2048] = inT@nodes  (512 blocks)
        gemm_d2<true ><<<dim3( 8, 32, 2), tb, 0, stream>>>(inM_bf, inMT_bf, nodesT,
            avn, 2048, 2048, 2048, 3072, 0, 1024);
        // zpre|rpre = avn @ [w3|w4]  (K=3072, 512 blocks)
        gemm_d2<false><<<dim3(16, 32, 1), tb, 0, stream>>>(avn, avn, Wzr_t,
            zrbuf, 3072, 3072, 3072, 2048, 0, 0);
        gates_zr_k<<<8192, tb, 0, stream>>>(zrbuf, nodes, zv, avn);
        // hpre(z) = avn[:, z*1536:] @ W5_t[:, z*1536:]  (split-K x2, 512 blocks)
        gemm_d2<false><<<dim3( 8, 32, 2), tb, 0, stream>>>(avn, avn, W5_t,
            hpre, 1536, 3072, 3072, 1024, 1536, 2097152);
        update_nodes_k<<<dim3(32, 64), tb, 0, stream>>>(nodes, zv, hpre, avn, ninit, nodesT);
    }

    // step_out partials = [nodes|init] @ fc_out_w  (split-K x2, 512 blocks)
    gemm_d2<false><<<dim3( 8, 32, 2), tb, 0, stream>>>(ninit, ninit, fcw_t,
        sop, 1024, 2048, 2048, 1024, 1024, 2097152);
    bias_l2<<<1024, tb, 0, stream>>>(sop, fcb, so_bf, partials);
    reduce_final<<<1, tb, 0, stream>>>(partials, out + (long)B * N);
    // output = x @ step_out^T  (2048 blocks)
    gemm_d2<false><<<dim3(16, 128, 1), tb, 0, stream>>>(x_bf, x_bf, so_bf,
        out, 1024, 1024, 1024, 2048, 0, 0);
}

// Round 6
// 445.685 us; speedup vs baseline: 12.3242x; 1.0369x over previous
//
#include <hip/hip_runtime.h>
#include <hip/hip_bf16.h>
#include <stdint.h>

// KGTN round 6.
// - GEMM: depth-1 schedule (R4's proven best: SYNC(vmcnt0+bar) -> STAGE(t+1)
//   -> COMPUTE(t)), 2 LDS buffers. Templated tile height: MFR=2 -> 64x128
//   (48 KiB, 3 blocks/CU) for GGNN GEMMs; MFR=4 -> 128x128 (64 KiB, 2
//   blocks/CU, m97 geometry) for the final x@so^T GEMM.
// - T1 bijective XCD swizzle on (y,x) linear id (all per-z grids %8==0).
// - T2 XOR swizzle (pre-swizzled source granule + swizzled read), T5 setprio.
// - zr GEMM epilogue fuses sigmoid: z-half blocks write zv fp32, r-half
//   blocks write rn_bf (separate buffer -> no RAW race on avn). gates_zr
//   kernel and zrbuf roundtrip eliminated.
// - h GEMM: balanced 3-way split-K (av-low | av-high | rn), partials summed
//   in update_nodes.

typedef __attribute__((ext_vector_type(8))) short bf16x8;
typedef __attribute__((ext_vector_type(4))) float f32x4;
typedef __attribute__((ext_vector_type(4))) ushort u16x4;

typedef __attribute__((address_space(3))) void lds_void;
typedef const __attribute__((address_space(1))) void gbl_void;

__device__ __forceinline__ ushort f2b(float v) {
    union { float f; uint32_t u; } c; c.f = v;
    uint32_t u = c.u + 0x7FFFu + ((c.u >> 16) & 1u);   // RNE; inputs finite
    return (ushort)(u >> 16);
}

// Tile: BM=MFR*32 x BN=128, BK=64. A row-major bf16, Bt=B^T row-major bf16.
// Grid: x=N/128, y=M/BM, z in {1,2,3} (per-z A/lda/B-col-offset/C-offset).
// EPI: 0 = fp32 C, 1 = bf16 C, 2 = fused sigmoid (zv / rn_bf, no C).
// Requires gridDim.x*gridDim.y % 8 == 0, K % 64 == 0, K/64 >= 2.
template <int MFR, int EPI>
__global__ __launch_bounds__(256) void gemm_t(
    const ushort* __restrict__ A0, const ushort* __restrict__ A1,
    const ushort* __restrict__ A2, const ushort* __restrict__ Bt,
    void* __restrict__ Cv, int K, long lda01, long lda2, long ldb, long ldc,
    long bKoff, long cOff, float* __restrict__ zvp, ushort* __restrict__ rnp,
    const float* __restrict__ nodesp)
{
    __shared__ ushort As[2 * MFR * 2048];   // 2 x BM x 64
    __shared__ ushort Bs[2 * 8192];         // 2 x 128 x 64
    const int tid  = threadIdx.x;
    const int lane = tid & 63;
    const int wave = tid >> 6;
    const int wr = (wave >> 1) * (MFR * 16);   // wave row band
    const int wc = (wave & 1) * 64;            // wave col band

    // T1: bijective XCD-chunked remap of linearized (y,x) id. nwg%8==0.
    const int gx  = gridDim.x;
    const int nwg = gx * gridDim.y;
    int bid = blockIdx.y * gx + blockIdx.x;
    bid = (bid & 7) * (nwg >> 3) + (bid >> 3);
    const long bm = (long)(bid / gx) * (MFR * 32);
    const long bn = (long)(bid % gx) * 128;
    const int z  = blockIdx.z;

    const ushort* A  = (z == 0) ? A0 : (z == 1) ? A1 : A2;
    const long lda   = (z == 2) ? lda2 : lda01;
    const ushort* Bp = Bt + (long)z * bKoff;

    const int l15  = lane & 15;
    const int kg   = lane >> 4;                    // 0..3
    const int srow = lane >> 3;                    // 0..7
    const int gsw  = ((lane & 7) ^ srow) & 7;      // pre-swizzled src granule

    f32x4 acc[MFR][4] = {};

    // stage one BK=64 K-tile (A: MFR slots/wave, B: 4 slots/wave)
    auto STAGE = [&](int k0, int buf) {
        #pragma unroll
        for (int p = 0; p < MFR; ++p) {
            const int slot = wave * MFR + p;       // BM/8 slots x 8 rows
            const int row  = slot * 8 + srow;
            const ushort* ga = A + (bm + row) * lda + (k0 + gsw * 8);
            __builtin_amdgcn_global_load_lds((gbl_void*)ga,
                (lds_void*)(As + buf * MFR * 2048 + slot * 512), 16, 0, 0);
        }
        #pragma unroll
        for (int p = 0; p < 4; ++p) {
            const int slot = wave * 4 + p;         // 16 slots x 8 rows = 128
            const int row  = slot * 8 + srow;
            const ushort* gb = Bp + (bn + row) * ldb + (k0 + gsw * 8);
            __builtin_amdgcn_global_load_lds((gbl_void*)gb,
                (lds_void*)(Bs + buf * 8192 + slot * 512), 16, 0, 0);
        }
    };

    auto COMPUTE = [&](int buf) {
        const ushort* as = As + buf * MFR * 2048;
        const ushort* bs = Bs + buf * 8192;
        #pragma unroll
        for (int kk = 0; kk < 2; ++kk) {
            const int ph = (((kk * 4 + kg) ^ (lane & 7)) & 7) * 8;
            bf16x8 af[MFR], bv[4];
            #pragma unroll
            for (int m = 0; m < MFR; ++m)
                af[m] = *(const bf16x8*)(as + (wr + m * 16 + l15) * 64 + ph);
            #pragma unroll
            for (int n = 0; n < 4; ++n)
                bv[n] = *(const bf16x8*)(bs + (wc + n * 16 + l15) * 64 + ph);
            __builtin_amdgcn_s_setprio(1);
            #pragma unroll
            for (int m = 0; m < MFR; ++m)
                #pragma unroll
                for (int n = 0; n < 4; ++n)
                    acc[m][n] = __builtin_amdgcn_mfma_f32_16x16x32_bf16(
                        af[m], bv[n], acc[m][n], 0, 0, 0);
            __builtin_amdgcn_s_setprio(0);
        }
    };

#define SYNC()                                              \
    __builtin_amdgcn_sched_barrier(0);                      \
    asm volatile("s_waitcnt vmcnt(0)" ::: "memory");        \
    __builtin_amdgcn_s_barrier();                           \
    __builtin_amdgcn_sched_barrier(0)

    const int T = K >> 6;
    STAGE(0, 0);
    for (int t = 0; t < T; ++t) {
        SYNC();                            // tile t landed; compute t-1 done
        if (t + 1 < T) STAGE((t + 1) * 64, (t + 1) & 1);
        COMPUTE(t & 1);
    }
#undef SYNC

    // C/D layout: col = lane&15, row = (lane>>4)*4 + reg   [m89-verified]
    const int cr0 = (lane >> 4) * 4;
    const bool zhalf = (bn < 1024);        // EPI2 only
    #pragma unroll
    for (int m = 0; m < MFR; ++m) {
        #pragma unroll
        for (int j = 0; j < 4; ++j) {
            const long r = bm + wr + m * 16 + cr0 + j;
            #pragma unroll
            for (int n = 0; n < 4; ++n) {
                const long c = bn + wc + n * 16 + l15;
                if (EPI == 0) {
                    ((float*)Cv + cOff * z)[r * ldc + c] = acc[m][n][j];
                } else if (EPI == 1) {
                    ((ushort*)Cv + cOff * z)[r * ldc + c] = f2b(acc[m][n][j]);
                } else {
                    const float s = 1.f / (1.f + __expf(-acc[m][n][j]));
                    if (zhalf) zvp[r * 1024 + c] = s;
                    else {
                        const long cc = c - 1024;
                        rnp[r * 1024 + cc] = f2b(s * nodesp[r * 1024 + cc]);
                    }
                }
            }
        }
    }
}

// fp32 -> bf16 elementwise, 4 elems/thread. n4 = total/4.
__global__ __launch_bounds__(256) void cvt_bf16_k(const float* __restrict__ src,
                                                  ushort* __restrict__ dst, long n4) {
    long i = (long)blockIdx.x * 256 + threadIdx.x;
    if (i >= n4) return;
    f32x4 v = *(const f32x4*)(src + i * 4);
    u16x4 o;
    #pragma unroll
    for (int j = 0; j < 4; ++j) o[j] = f2b(v[j]);
    *(u16x4*)(dst + i * 4) = o;
}

// dst[c*dld + r] = bf16(src[r*C + c]). Grid (C/32, R/32), block 256.
__global__ __launch_bounds__(256) void transpose_cvt(const float* __restrict__ src,
                                                     ushort* __restrict__ dst,
                                                     int R, int C, int dld) {
    __shared__ float t[32][33];
    const int c0 = blockIdx.x * 32, r0 = blockIdx.y * 32;
    const int tx = threadIdx.x & 31, ty = threadIdx.x >> 5;
    #pragma unroll
    for (int i = 0; i < 32; i += 8)
        t[ty + i][tx] = src[(long)(r0 + ty + i) * C + c0 + tx];
    __syncthreads();
    #pragma unroll
    for (int i = 0; i < 32; i += 8)
        dst[(long)(c0 + ty + i) * dld + r0 + tx] = f2b(t[tx][ty + i]);
}

// From lfw [1024(h), 2048(N)]: nodesT_bf[h][N], nodes f32 [N][h],
// nodes_bf -> avn cols 2048:3072, init_bf -> ninit cols 1024:2048.
__global__ __launch_bounds__(256) void init_nodes_k(const float* __restrict__ lfw,
        ushort* __restrict__ nodesT, float* __restrict__ nodes,
        ushort* __restrict__ avn, ushort* __restrict__ ninit) {
    __shared__ float t[32][33];
    const int n0 = blockIdx.x * 32, h0 = blockIdx.y * 32;
    const int tx = threadIdx.x & 31, ty = threadIdx.x >> 5;
    #pragma unroll
    for (int i = 0; i < 32; i += 8) {
        float v = lfw[(long)(h0 + ty + i) * 2048 + n0 + tx];
        nodesT[(long)(h0 + ty + i) * 2048 + n0 + tx] = f2b(v);
        t[ty + i][tx] = v;
    }
    __syncthreads();
    #pragma unroll
    for (int i = 0; i < 32; i += 8) {
        const int n = n0 + ty + i, hh = h0 + tx;
        float v = t[tx][ty + i];
        nodes[(long)n * 1024 + hh] = v;
        ushort b = f2b(v);
        avn[(long)n * 3072 + 2048 + hh] = b;
        ninit[(long)n * 2048 + 1024 + hh] = b;
    }
}

// nodes = (1-z)*nodes + z*tanh(hp0+hp1+hp2); emit nodes_bf + transposed copy.
__global__ __launch_bounds__(256) void update_nodes_k(float* __restrict__ nodes,
        const float* __restrict__ zv, const float* __restrict__ hp,
        ushort* __restrict__ avn, ushort* __restrict__ ninit,
        ushort* __restrict__ nodesT) {
    __shared__ float t[32][33];
    const int c0 = blockIdx.x * 32, r0 = blockIdx.y * 32;
    const int tx = threadIdx.x & 31, ty = threadIdx.x >> 5;
    #pragma unroll
    for (int i = 0; i < 32; i += 8) {
        const int r = r0 + ty + i, c = c0 + tx;
        const long idx = (long)r * 1024 + c;
        const float z = zv[idx];
        const float hsum = hp[idx] + hp[idx + 2097152] + hp[idx + 4194304];
        const float nn = (1.f - z) * nodes[idx] + z * tanhf(hsum);
        nodes[idx] = nn;
        const ushort b = f2b(nn);
        avn[(long)r * 3072 + 2048 + c] = b;
        ninit[(long)r * 2048 + c] = b;
        t[ty + i][tx] = nn;
    }
    __syncthreads();
    #pragma unroll
    for (int i = 0; i < 32; i += 8)
        nodesT[(long)(c0 + ty + i) * 2048 + r0 + tx] = f2b(t[tx][ty + i]);
}

// v = sop0+sop1+bias; so_bf = bf16(v); partial sums of v^2. 1024 blocks.
__global__ __launch_bounds__(256) void bias_l2(const float* __restrict__ s,
        const float* __restrict__ bias, ushort* __restrict__ so_bf,
        float* __restrict__ partials) {
    __shared__ float red[256];
    const int tid = threadIdx.x;
    const long base = (long)blockIdx.x * 2048;
    float sum = 0.f;
    #pragma unroll
    for (int it = 0; it < 8; ++it) {
        const long i = base + tid + it * 256;
        const float v = s[i] + s[i + 2097152] + bias[i & 1023];
        so_bf[i] = f2b(v);
        sum += v * v;
    }
    red[tid] = sum;
    __syncthreads();
    #pragma unroll
    for (int w = 128; w > 0; w >>= 1) {
        if (tid < w) red[tid] += red[tid + w];
        __syncthreads();
    }
    if (tid == 0) partials[blockIdx.x] = red[0];
}

__global__ __launch_bounds__(256) void reduce_final(const float* __restrict__ partials,
                                                    float* __restrict__ out) {
    __shared__ float red[256];
    const int tid = threadIdx.x;
    red[tid] = partials[tid] + partials[tid + 256] + partials[tid + 512] + partials[tid + 768];
    __syncthreads();
    #pragma unroll
    for (int w = 128; w > 0; w >>= 1) {
        if (tid < w) red[tid] += red[tid + w];
        __syncthreads();
    }
    if (tid == 0) out[0] = red[0];
}

extern "C" void kernel_launch(void* const* d_in, const int* in_sizes, int n_in,
                              void* d_out, int out_size, void* d_ws, size_t ws_size,
                              hipStream_t stream) {
    const float* x   = (const float*)d_in[0];   // [8192,1024]
    const float* lfw = (const float*)d_in[1];   // [1024,2048]
    const float* inM = (const float*)d_in[2];   // [2048,2048]
    const float* w3w = (const float*)d_in[3];
    const float* w3u = (const float*)d_in[4];
    const float* w4w = (const float*)d_in[5];
    const float* w4u = (const float*)d_in[6];
    const float* w5w = (const float*)d_in[7];
    const float* w5u = (const float*)d_in[8];
    const float* fcw = (const float*)d_in[9];
    const float* fcb = (const float*)d_in[10];
    float* out = (float*)d_out;

    const int B = 8192, N = 2048;
    const long NH = 2097152;

    // d_out front as fp32 scratch (dead before final GEMM rewrites d_out):
    float* hpre = out;                  // 3x [2048,1024] (24MB)
    float* sop  = out + 6291456l;       // 2x [2048,1024] (16MB)

    char* p = (char*)d_ws;
    auto alloc = [&](size_t bytes) {
        char* r = p; p += (bytes + 255) & ~(size_t)255; return r;
    };
    float*  nodes    = (float*)alloc(NH * 4);
    float*  zv       = (float*)alloc(NH * 4);
    float*  partials = (float*)alloc(1024 * 4);
    ushort* avn      = (ushort*)alloc(6291456ull * 2);  // [2048,3072]
    ushort* rn_bf    = (ushort*)alloc(NH * 2);          // [2048,1024]
    ushort* nodesT   = (ushort*)alloc(NH * 2);          // [1024,2048]
    ushort* ninit    = (ushort*)alloc(4194304ull * 2);  // [2048,2048]
    ushort* inM_bf   = (ushort*)alloc(4194304ull * 2);
    ushort* inMT_bf  = (ushort*)alloc(4194304ull * 2);
    ushort* Wzr_t    = (ushort*)alloc(6291456ull * 2);  // [2048,3072]
    ushort* W5_t     = (ushort*)alloc(3145728ull * 2);  // [1024,3072]
    ushort* fcw_t    = (ushort*)alloc(NH * 2);          // [1024,2048]
    ushort* x_bf     = (ushort*)alloc(8388608ull * 2);  // [8192,1024]
    ushort* so_bf    = (ushort*)alloc(NH * 2);          // [2048,1024]

    const dim3 tb(256);

    // ---- prep ----
    cvt_bf16_k<<<8192, tb, 0, stream>>>(x, x_bf, 2097152);
    cvt_bf16_k<<<4096, tb, 0, stream>>>(inM, inM_bf, 1048576);
    transpose_cvt<<<dim3(64, 64), tb, 0, stream>>>(inM, inMT_bf, 2048, 2048, 2048);
    transpose_cvt<<<dim3(32, 64), tb, 0, stream>>>(w3w, Wzr_t,                    2048, 1024, 3072);
    transpose_cvt<<<dim3(32, 32), tb, 0, stream>>>(w3u, Wzr_t + 2048,             1024, 1024, 3072);
    transpose_cvt<<<dim3(32, 64), tb, 0, stream>>>(w4w, Wzr_t + 3145728l,         2048, 1024, 3072);
    transpose_cvt<<<dim3(32, 32), tb, 0, stream>>>(w4u, Wzr_t + 3145728l + 2048,  1024, 1024, 3072);
    transpose_cvt<<<dim3(32, 64), tb, 0, stream>>>(w5w, W5_t,                     2048, 1024, 3072);
    transpose_cvt<<<dim3(32, 32), tb, 0, stream>>>(w5u, W5_t + 2048,              1024, 1024, 3072);
    transpose_cvt<<<dim3(32, 64), tb, 0, stream>>>(fcw, fcw_t,                    2048, 1024, 2048);
    init_nodes_k<<<dim3(64, 32), tb, 0, stream>>>(lfw, nodesT, nodes, avn, ninit);

    // ---- GGNN time steps ----
    for (int t = 0; t < 3; ++t) {
        // avn[:,0:1024] = in@nodes ; avn[:,1024:2048] = inT@nodes (512 blocks)
        gemm_t<2, 1><<<dim3(8, 32, 2), tb, 0, stream>>>(
            inM_bf, inMT_bf, nullptr, nodesT, avn,
            2048, 2048, 0, 2048, 3072, 0, 1024, nullptr, nullptr, nullptr);
        // fused zr: zv = sigmoid(avn@[w3]), rn_bf = sigmoid(avn@[w4])*nodes
        gemm_t<2, 2><<<dim3(16, 32, 1), tb, 0, stream>>>(
            avn, nullptr, nullptr, Wzr_t, nullptr,
            3072, 3072, 0, 3072, 0, 0, 0, zv, rn_bf, nodes);
        // hpre(z) partials: z0 = avn[:,0:1024]@W5[0:1024], z1 = avn[:,1024:2048]
        //   @W5[1024:2048], z2 = rn_bf@W5[2048:3072]   (768 blocks, balanced)
        gemm_t<2, 0><<<dim3(8, 32, 3), tb, 0, stream>>>(
            avn, avn + 1024, rn_bf, W5_t, hpre,
            1024, 3072, 1024, 3072, 1024, 1024, 2097152, nullptr, nullptr, nullptr);
        update_nodes_k<<<dim3(32, 64), tb, 0, stream>>>(nodes, zv, hpre, avn, ninit, nodesT);
    }

    // step_out partials = [nodes|init] @ fc_out_w  (split-K x2, 512 blocks)
    gemm_t<2, 0><<<dim3(8, 32, 2), tb, 0, stream>>>(
        ninit, ninit + 1024, nullptr, fcw_t, sop,
        1024, 2048, 0, 2048, 1024, 1024, 2097152, nullptr, nullptr, nullptr);
    bias_l2<<<1024, tb, 0, stream>>>(sop, fcb, so_bf, partials);
    reduce_final<<<1, tb, 0, stream>>>(partials, out + (long)B * N);
    // output = x @ step_out^T  (128x128 tile, 1024 blocks, 2 blocks/CU)
    gemm_t<4, 0><<<dim3(16, 64, 1), tb, 0, stream>>>(
        x_bf, nullptr, nullptr, so_bf, out,
        1024, 1024, 0, 1024, 2048, 0, 0, nullptr, nullptr, nullptr);
}